// Round 5
// baseline (217.537 us; speedup 1.0000x reference)
//
#include <hip/hip_runtime.h>
#include <math.h>

#define SL 1024      // sequence length (H*W)
#define CH 384       // channels
#define NHEAD 8
#define DH 48        // head dim (dk == dv)
#define NBIAS 3969
#define NTOK 8192    // B * SL
#define BATCH 8
#define CFF 1536
#define LN_EPS 1e-5f
#define QKVLD 1152
#define HMS 3145728   // shorts per head-major tensor: B*NH*SL*48
#define KHMS 4194304  // shorts for padded K: B*NH*SL*64
#define NROWS 65536   // B*NH*SL
#define LOG2E 1.4426950408889634f

// bf16 weight pool layout (element offsets)
#define WQKV_OFF 0
#define WO_OFF   442368
#define F1_OFF   589824
#define F2_OFF   1179648
#define WTOT     1769472

typedef float floatx4 __attribute__((ext_vector_type(4)));
typedef short bf16x8 __attribute__((ext_vector_type(8)));

__device__ __forceinline__ unsigned f2bf_u(float f) {
  unsigned u = __float_as_uint(f);
  return (u + 0x7fffu + ((u >> 16) & 1u)) >> 16;
}
__device__ __forceinline__ unsigned pack2(float a, float b) {
  return f2bf_u(a) | (f2bf_u(b) << 16);
}
__device__ __forceinline__ float bf2f(short s) {
  return __uint_as_float(((unsigned)(unsigned short)s) << 16);
}
// single-instruction packed f32x2 -> bf16x2 (RNE, same as f2bf_u)
__device__ __forceinline__ unsigned cvtpk(float lo, float hi) {
  unsigned r;
  asm("v_cvt_pk_bf16_f32 %0, %1, %2" : "=v"(r) : "v"(lo), "v"(hi));
  return r;
}

// async global->LDS, 16B per lane; lds base must be wave-uniform
__device__ __forceinline__ void gload_lds16(const void* g, void* l) {
  __builtin_amdgcn_global_load_lds(
      (const __attribute__((address_space(1))) void*)g,
      (__attribute__((address_space(3))) void*)l, 16, 0, 0);
}

// ---------------- weights fp32 -> bf16 pool ----------------
__global__ void k_w2bf(const float* __restrict__ Wq, const float* __restrict__ Wk,
                       const float* __restrict__ Wv, const float* __restrict__ Wo,
                       const float* __restrict__ f1, const float* __restrict__ f2,
                       short* __restrict__ dst) {
  size_t i = ((size_t)blockIdx.x * 256 + threadIdx.x) * 8;
  if (i >= WTOT) return;
  const float* s;
  size_t base;
  if (i < 147456)        { s = Wq; base = 0; }
  else if (i < 294912)   { s = Wk; base = 147456; }
  else if (i < WO_OFF)   { s = Wv; base = 294912; }
  else if (i < F1_OFF)   { s = Wo; base = WO_OFF; }
  else if (i < F2_OFF)   { s = f1; base = F1_OFF; }
  else                   { s = f2; base = F2_OFF; }
  const float4* p = (const float4*)(s + (i - base));
  float4 a = p[0], b = p[1];
  uint4 o;
  o.x = pack2(a.x, a.y); o.y = pack2(a.z, a.w);
  o.z = pack2(b.x, b.y); o.w = pack2(b.z, b.w);
  *(uint4*)(dst + i) = o;
}

// ---------------- fused transpose + LayerNorm: x (B,C,L) -> tok_bf (B*L, C) ----
__global__ __launch_bounds__(256) void k_ln_fused(
    const float* __restrict__ x, const float* __restrict__ gamma,
    const float* __restrict__ beta, short* __restrict__ tok) {
  __shared__ float sx[32][385];  // [l][c]
  int b = blockIdx.y, l0 = blockIdx.x * 32;
  int tid = threadIdx.x;
  const float* xb = x + (size_t)b * CH * SL;
  int cr = tid >> 3, ls = (tid & 7) * 4;
#pragma unroll
  for (int c0 = 0; c0 < CH; c0 += 32) {
    int c = c0 + cr;
    float4 v = *(const float4*)(xb + (size_t)c * SL + l0 + ls);
    sx[ls + 0][c] = v.x; sx[ls + 1][c] = v.y;
    sx[ls + 2][c] = v.z; sx[ls + 3][c] = v.w;
  }
  __syncthreads();
  int tl = tid >> 3, p = tid & 7;  // 8 threads per token, 48 channels each
  float vals[48];
  float s = 0.f, q = 0.f;
#pragma unroll
  for (int i = 0; i < 48; i++) {
    float v = sx[tl][p * 48 + i];
    vals[i] = v; s += v; q += v * v;
  }
  s += __shfl_xor(s, 1, 64); q += __shfl_xor(q, 1, 64);
  s += __shfl_xor(s, 2, 64); q += __shfl_xor(q, 2, 64);
  s += __shfl_xor(s, 4, 64); q += __shfl_xor(q, 4, 64);
  float mu = s * (1.0f / CH);
  float rstd = rsqrtf(q * (1.0f / CH) - mu * mu + LN_EPS);
  short* orow = tok + (size_t)(b * SL + l0 + tl) * CH + p * 48;
#pragma unroll
  for (int i = 0; i < 48; i += 2) {
    float a = (vals[i] - mu) * rstd * gamma[p * 48 + i] + beta[p * 48 + i];
    float c = (vals[i + 1] - mu) * rstd * gamma[p * 48 + i + 1] + beta[p * 48 + i + 1];
    *(unsigned*)(orow + i) = pack2(a, c);
  }
}

// ---------------- bf16 MFMA GEMM: C(M,N) = A(M,K) @ W(N,K)^T ----------------
// Tile BMx128, BK=64. 256 thr = 4 waves 2x2; wave-tile (BM/2)x64.
// RES_MODE: 0 none, 1 row-major fp32, 2 x-layout (B,C,L) fp32.
// OUT_MODE bits: 1 f32 row-major Cf, 2 bf16 Cb, 4 f32 (B,C,L) Ct,
//  8 bf16 qkv split: Q -> Chm (bh,m,48); K -> Ckm (bh,m,64) pad-zeroed +
//  XOR bank-swizzle baked; V -> Cvm (bh,d,SL) transposed with PV slot
//  permutation sigma + XOR swizzle baked (attn stages via pure gload_lds).
template <int BM, bool GELU, bool HAS_BIAS, int RES_MODE, int OUT_MODE>
__global__ __launch_bounds__(256) void k_gemm_mfma(
    const short* __restrict__ A, const short* __restrict__ W,
    const float* __restrict__ bias, const float* __restrict__ res,
    float* __restrict__ Cf, short* __restrict__ Cb, float* __restrict__ Ct,
    short* __restrict__ Chm, short* __restrict__ Ckm, short* __restrict__ Cvm,
    int N, int K) {
  constexpr int MI = BM / 32;
  constexpr int ASI = BM * 2 / 64;
  __shared__ short As[BM * 64];
  __shared__ short Bs[128 * 64];
  int tid = threadIdx.x;
  int wid = tid >> 6, lane = tid & 63;
  int lanelo = lane & 15, quad = lane >> 4;
  int wm = wid & 1, wn = wid >> 1;
  int m0 = blockIdx.y * BM, n0 = blockIdx.x * 128;

  const short* Aga[ASI];
  short* Ala[ASI];
#pragma unroll
  for (int s = 0; s < ASI; s++) {
    int p = wid * (BM * 2) + s * 64 + lane;
    int row = p >> 3, ch = (p & 7) ^ (row & 7);
    Aga[s] = A + (size_t)(m0 + row) * K + ch * 8;
    Ala[s] = As + (wid * (BM * 2) + s * 64) * 8;
  }
  const short* Bga[4];
  short* Bla[4];
#pragma unroll
  for (int s = 0; s < 4; s++) {
    int p = wid * 256 + s * 64 + lane;
    int row = p >> 3, ch = (p & 7) ^ (row & 7);
    Bga[s] = W + (size_t)(n0 + row) * K + ch * 8;
    Bla[s] = Bs + (wid * 256 + s * 64) * 8;
  }

  floatx4 acc[MI][4];
#pragma unroll
  for (int i = 0; i < MI; i++)
#pragma unroll
    for (int j = 0; j < 4; j++) acc[i][j] = {0.f, 0.f, 0.f, 0.f};

  int x8 = lanelo & 7;
  int ca0 = (quad ^ x8) * 8;
  int ca1 = ((quad + 4) ^ x8) * 8;

  for (int k0 = 0; k0 < K; k0 += 64) {
    __syncthreads();
#pragma unroll
    for (int s = 0; s < ASI; s++) gload_lds16(Aga[s] + k0, Ala[s]);
#pragma unroll
    for (int s = 0; s < 4; s++) gload_lds16(Bga[s] + k0, Bla[s]);
    __syncthreads();
#pragma unroll
    for (int h = 0; h < 2; h++) {
      int co = h ? ca1 : ca0;
      bf16x8 af[MI], bq[4];
#pragma unroll
      for (int i = 0; i < MI; i++)
        af[i] = *(const bf16x8*)&As[(wm * (BM / 2) + i * 16 + lanelo) * 64 + co];
#pragma unroll
      for (int j = 0; j < 4; j++)
        bq[j] = *(const bf16x8*)&Bs[(wn * 64 + j * 16 + lanelo) * 64 + co];
#pragma unroll
      for (int i = 0; i < MI; i++)
#pragma unroll
        for (int j = 0; j < 4; j++)
          acc[i][j] = __builtin_amdgcn_mfma_f32_16x16x32_bf16(af[i], bq[j], acc[i][j], 0, 0, 0);
    }
  }

  // epilogue: C/D row=(lane>>4)*4+reg, col=lane&15; reg = 4 consecutive tokens.
  int colb = n0 + wn * 64 + lanelo;
  float bvv[4];
#pragma unroll
  for (int j = 0; j < 4; j++) bvv[j] = HAS_BIAS ? bias[colb + j * 16] : 0.0f;
#pragma unroll
  for (int i = 0; i < MI; i++) {
    int r = m0 + wm * (BM / 2) + i * 16 + quad * 4;
    int bb = r >> 10, ll = r & 1023;
#pragma unroll
    for (int j = 0; j < 4; j++) {
      int c = colb + j * 16;
      float4 rv = {0.f, 0.f, 0.f, 0.f};
      if (RES_MODE == 2) rv = *(const float4*)(res + ((size_t)bb * CH + c) * SL + ll);
      float vv[4];
#pragma unroll
      for (int reg = 0; reg < 4; reg++) {
        float v = acc[i][j][reg] + bvv[j];
        if (RES_MODE == 1) v += res[(size_t)(r + reg) * N + c];
        if (RES_MODE == 2) v += (&rv.x)[reg];
        if (GELU) v = 0.5f * v * (1.0f + erff(v * 0.7071067811865476f));
        vv[reg] = v;
      }
      if (OUT_MODE & 1) {
#pragma unroll
        for (int reg = 0; reg < 4; reg++) Cf[(size_t)(r + reg) * N + c] = vv[reg];
      }
      if (OUT_MODE & 2) {
#pragma unroll
        for (int reg = 0; reg < 4; reg++) Cb[(size_t)(r + reg) * N + c] = (short)f2bf_u(vv[reg]);
      }
      if (OUT_MODE & 4) {
        float4 ov = {vv[0], vv[1], vv[2], vv[3]};
        *(float4*)(Ct + ((size_t)bb * CH + c) * SL + ll) = ov;
      }
      if (OUT_MODE & 8) {
        int part = c / 384;
        int rem = c - part * 384;
        int hh = rem / 48, dd = rem - hh * 48;
        int bhh = bb * NHEAD + hh;
        if (part == 0) {
          short* dst = Chm + ((size_t)bhh * SL + ll) * 48 + dd;
#pragma unroll
          for (int reg = 0; reg < 4; reg++) dst[reg * 48] = (short)f2bf_u(vv[reg]);
        } else if (part == 1) {
          // padded 64-col rows; 16B-slot index XORed with (m&7)
          short* dst = Ckm + ((size_t)bhh * SL + ll) * 64;
#pragma unroll
          for (int reg = 0; reg < 4; reg++) {
            int mm = (ll + reg) & 7;
            dst[reg * 64 + (dd & 7) + (((dd >> 3) ^ mm) << 3)] = (short)f2bf_u(vv[reg]);
            if (dd < 16)  // zero the pad cols 48..63 (slots 6,7)
              dst[reg * 64 + (dd & 7) + ((((dd + 48) >> 3) ^ mm) << 3)] = 0;
          }
        } else {
          // V^T (d-major) with PV slot permutation sigma + XOR swizzle baked
          int kk = ll & 63;
          int sig = ((kk >> 2) & 3) * 8 + ((kk >> 4) & 1) * 4 + (kk >> 5) * 32;
          int mcol = (ll & ~63) + (sig ^ ((dd & 7) << 3));
          uint2 pk = {pack2(vv[0], vv[1]), pack2(vv[2], vv[3])};
          *(uint2*)(Cvm + ((size_t)bhh * 48 + dd) * SL + mcol) = pk;
        }
      }
    }
  }
}

// ---------------- MFMA flash attention, round-5 structure -------------------
// Per block: 128 threads (2 waves x 64 q-rows), one (b,h), key-half split
// (ks in {0,1}, 512 keys, 8 m-tiles). Partials: op[ks] unnormalized bf16 O,
// ls[ks] fp32 denominators; combined by k_attn_combine (round-2 infra).
// Counter-model (r4): per-CU LDS issue pipe was the binding term (4 waves x
// identical frag reads + 32 scalar bias reads/lane/tile). Changes:
//  - K/V staged by pure global_load_lds DMA (zero staging VALU/LDS-writes);
//    swizzle + sigma permutation pre-baked into GLOBAL layouts by the QKV
//    GEMM (both-sides-or-neither rule), LDS dest linear.
//  - 64 q-rows/wave halves redundant K/V fragment reads per q-row.
//  - bias: 4x-shifted float4 table -> ds_read_b128; bidx depends only on
//    nt-qi -> 7 reads/tile/lane instead of 32 scalar.
//  - softmax denominators via ones-row MFMA (VALU adds -> idle MFMA pipe).
__global__ __launch_bounds__(128) void k_attn_mfma(
    const short* __restrict__ qh, const short* __restrict__ kh,
    const short* __restrict__ vt, const float* __restrict__ rel_bias,
    short* __restrict__ op, float* __restrict__ ls) {
  __shared__ short QP[128 * 72];     // bias table (loop) / O^T transpose (epilogue)
  __shared__ short Ks[2][64 * 64];   // padded+swizzled K tiles (DMA image)
  __shared__ short Vts[2][64 * 64];  // rows 0..47 V^T tile; 48 ones; 49..63 zero
  float4* Bt = (float4*)QP;

  int ksp = blockIdx.x & 1;
  int l0 = (blockIdx.x >> 1) * 128;
  int ms = ksp * 512;
  int b = blockIdx.z, h = blockIdx.y;
  int tid = threadIdx.x;
  int wid = tid >> 6, lane = tid & 63;
  int lanelo = lane & 15, quad = lane >> 4;
  int bh = b * NHEAD + h;
  size_t hb = (size_t)bh * SL;
  const short* kbase = kh + ((size_t)bh * SL + ms) * 64;
  const short* vtbase = vt + (size_t)bh * 48 * SL + ms;

  // ---- Q fragments direct from global (pad c>=48 contributes zero) ----
  bf16x8 aq[4][2];
  bf16x8 zf = {0, 0, 0, 0, 0, 0, 0, 0};
#pragma unroll
  for (int qi = 0; qi < 4; qi++) {
    const short* qsrc = qh + (hb + l0 + wid * 64 + qi * 16 + lanelo) * 48;
    aq[qi][0] = *(const bf16x8*)(qsrc + quad * 8);
    aq[qi][1] = (quad < 2) ? *(const bf16x8*)(qsrc + 32 + quad * 8) : zf;
  }

  // ---- bias table: Bt[j] = band[j..j+3] * log2e (one b128 per 4 values) ----
  {
    const float* bsrc = rel_bias + h * NBIAS + (929 - l0 + ms);
    for (int j = tid; j < 640; j += 128) {
      float4 t;
      t.x = bsrc[j] * LOG2E;     t.y = bsrc[j + 1] * LOG2E;
      t.z = bsrc[j + 2] * LOG2E; t.w = bsrc[j + 3] * LOG2E;
      Bt[j] = t;
    }
  }
  // ---- Vts rows 48..63: row 48 = ones (lsum via MFMA), rest zero ----
  for (int z = tid; z < 1024; z += 128) {
    int bi = z >> 9, o = z & 511;
    int row = 48 + (o >> 5), colu = o & 31;
    ((unsigned*)&Vts[bi][row * 64])[colu] = (row == 48) ? 0x3F803F80u : 0u;
  }
  // ---- stage tile 0 (pure DMA) ----
#pragma unroll
  for (int c = 0; c < 4; c++)
    gload_lds16(kbase + (size_t)(c * 128 + tid) * 8, &Ks[0][(c * 128 + wid * 64) * 8]);
#pragma unroll
  for (int c = 0; c < 3; c++) {
    int g = c * 128 + tid;
    gload_lds16(vtbase + (size_t)(g >> 3) * SL + (g & 7) * 8,
                &Vts[0][(c * 128 + wid * 64) * 8]);
  }
  __syncthreads();

  floatx4 O[3][4];  // O^T accum: [dt][qi], row=d=quad*4+reg, col=q=lanelo
  floatx4 O3[4];    // ones-row accum: row0 = softmax denominators
#pragma unroll
  for (int qi = 0; qi < 4; qi++) {
#pragma unroll
    for (int dt = 0; dt < 3; dt++) O[dt][qi] = {0.f, 0.f, 0.f, 0.f};
    O3[qi] = {0.f, 0.f, 0.f, 0.f};
  }
  int swz = (lanelo & 7) << 3;
  int base00 = 127 + quad * 4 - wid * 64 - lanelo;

  int cur = 0;
  for (int mt = 0; mt < 512; mt += 64) {
    // issue next-tile DMA early; lands before the end-of-iter barrier drain
    if (mt + 64 < 512) {
      int nxt = cur ^ 1, mtn = mt + 64;
#pragma unroll
      for (int c = 0; c < 4; c++)
        gload_lds16(kbase + (size_t)mtn * 64 + (size_t)(c * 128 + tid) * 8,
                    &Ks[nxt][(c * 128 + wid * 64) * 8]);
#pragma unroll
      for (int c = 0; c < 3; c++) {
        int g = c * 128 + tid;
        gload_lds16(vtbase + (size_t)(g >> 3) * SL + mtn + (g & 7) * 8,
                    &Vts[nxt][(c * 128 + wid * 64) * 8]);
      }
    }

    // fragments (swizzled reads match the pre-swizzled global image)
    bf16x8 kb[4][2], vf[3][2], vo[2];
#pragma unroll
    for (int nt = 0; nt < 4; nt++) {
      kb[nt][0] = *(const bf16x8*)&Ks[cur][(nt * 16 + lanelo) * 64 + ((quad * 8) ^ swz)];
      kb[nt][1] = *(const bf16x8*)&Ks[cur][(nt * 16 + lanelo) * 64 + ((32 + quad * 8) ^ swz)];
    }
#pragma unroll
    for (int dt = 0; dt < 3; dt++) {
      vf[dt][0] = *(const bf16x8*)&Vts[cur][(dt * 16 + lanelo) * 64 + ((quad * 8) ^ swz)];
      vf[dt][1] = *(const bf16x8*)&Vts[cur][(dt * 16 + lanelo) * 64 + ((32 + quad * 8) ^ swz)];
    }
    vo[0] = *(const bf16x8*)&Vts[cur][(48 + lanelo) * 64 + ((quad * 8) ^ swz)];
    vo[1] = *(const bf16x8*)&Vts[cur][(48 + lanelo) * 64 + ((32 + quad * 8) ^ swz)];

    // bias: 7 shared float4 rows cover all 16 (qi,nt) pairs (index nt-qi)
    float4 bv[7];
    int b0 = base00 + mt;
#pragma unroll
    for (int t = 0; t < 7; t++) bv[t] = Bt[b0 + 16 * t - 48];

#pragma unroll
    for (int qi = 0; qi < 4; qi++) {
      floatx4 sc[4];
#pragma unroll
      for (int nt = 0; nt < 4; nt++) {
        floatx4 a = {0.f, 0.f, 0.f, 0.f};
        a = __builtin_amdgcn_mfma_f32_16x16x32_bf16(kb[nt][0], aq[qi][0], a, 0, 0, 0);
        a = __builtin_amdgcn_mfma_f32_16x16x32_bf16(kb[nt][1], aq[qi][1], a, 0, 0, 0);
        sc[nt] = a;
      }
      union U8 { unsigned u[4]; bf16x8 v; } pb0, pb1;
#pragma unroll
      for (int nt = 0; nt < 4; nt++) {
        float4 bb = bv[nt - qi + 3];
        float e0 = __builtin_amdgcn_exp2f(fmaf(sc[nt][0], LOG2E, bb.x));
        float e1 = __builtin_amdgcn_exp2f(fmaf(sc[nt][1], LOG2E, bb.y));
        float e2 = __builtin_amdgcn_exp2f(fmaf(sc[nt][2], LOG2E, bb.z));
        float e3 = __builtin_amdgcn_exp2f(fmaf(sc[nt][3], LOG2E, bb.w));
        unsigned p01 = cvtpk(e0, e1), p23 = cvtpk(e2, e3);
        if (nt == 0)      { pb0.u[0] = p01; pb0.u[1] = p23; }
        else if (nt == 1) { pb0.u[2] = p01; pb0.u[3] = p23; }
        else if (nt == 2) { pb1.u[0] = p01; pb1.u[1] = p23; }
        else              { pb1.u[2] = p01; pb1.u[3] = p23; }
      }
#pragma unroll
      for (int dt = 0; dt < 3; dt++) {
        O[dt][qi] = __builtin_amdgcn_mfma_f32_16x16x32_bf16(vf[dt][0], pb0.v, O[dt][qi], 0, 0, 0);
        O[dt][qi] = __builtin_amdgcn_mfma_f32_16x16x32_bf16(vf[dt][1], pb1.v, O[dt][qi], 0, 0, 0);
      }
      O3[qi] = __builtin_amdgcn_mfma_f32_16x16x32_bf16(vo[0], pb0.v, O3[qi], 0, 0, 0);
      O3[qi] = __builtin_amdgcn_mfma_f32_16x16x32_bf16(vo[1], pb1.v, O3[qi], 0, 0, 0);
    }
    __syncthreads();  // drains vmcnt (next tile landed) + all cur readers done
    cur ^= 1;
  }

  // ---- epilogue: denominators from ones-row, unnormalized O^T -> op ----
  if (quad == 0) {
#pragma unroll
    for (int qi = 0; qi < 4; qi++)
      ls[(size_t)ksp * NROWS + hb + l0 + wid * 64 + qi * 16 + lanelo] = O3[qi][0];
  }
#pragma unroll
  for (int dt = 0; dt < 3; dt++)
#pragma unroll
    for (int qi = 0; qi < 4; qi++) {
      uint2 wv = {cvtpk(O[dt][qi][0], O[dt][qi][1]),
                  cvtpk(O[dt][qi][2], O[dt][qi][3])};
      *(uint2*)&QP[(wid * 64 + qi * 16 + lanelo) * 72 + dt * 16 + quad * 4] = wv;
    }
  __asm__ volatile("s_waitcnt lgkmcnt(0)" ::: "memory");  // wave-local transpose
#pragma unroll
  for (int c = 0; c < 6; c++) {
    int g = c * 64 + lane;
    int rl = g / 6, pos = g - rl * 6;
    int rowl = wid * 64 + rl;
    uint4 val = *(const uint4*)&QP[rowl * 72 + pos * 8];
    *(uint4*)(op + (size_t)ksp * HMS + (hb + l0 + rowl) * 48 + pos * 8) = val;
  }
}

// ---------------- combine: ao = (O0 + O1) / (l0 + l1), bf16 token-major ----
__global__ __launch_bounds__(256) void k_attn_combine(
    const short* __restrict__ op, const float* __restrict__ ls,
    short* __restrict__ ao) {
  int gid = blockIdx.x * 256 + threadIdx.x;  // 393216 granules of 8
  int row = gid / 6, ch = gid - row * 6;
  float inv = 1.0f / (ls[row] + ls[NROWS + row]);
  bf16x8 va = *(const bf16x8*)(op + (size_t)row * 48 + ch * 8);
  bf16x8 vb = *(const bf16x8*)(op + (size_t)HMS + (size_t)row * 48 + ch * 8);
  int b = row >> 13, h = (row >> 10) & 7, q = row & 1023;
  short* dst = ao + ((size_t)(b << 10) + q) * CH + h * 48 + ch * 8;
  unsigned outw[4];
#pragma unroll
  for (int j = 0; j < 4; j++) {
    float a0 = bf2f(va[2 * j]), a1 = bf2f(va[2 * j + 1]);
    float b0 = bf2f(vb[2 * j]), b1 = bf2f(vb[2 * j + 1]);
    outw[j] = pack2((a0 + b0) * inv, (a1 + b1) * inv);
  }
  *(uint4*)dst = *(uint4*)outw;
}

// ---------------- launch ----------------
extern "C" void kernel_launch(void* const* d_in, const int* in_sizes, int n_in,
                              void* d_out, int out_size, void* d_ws, size_t ws_size,
                              hipStream_t stream) {
  const float* x = (const float*)d_in[0];
  const float* gamma = (const float*)d_in[1];
  const float* beta = (const float*)d_in[2];
  const float* Wq = (const float*)d_in[3];
  const float* Wk = (const float*)d_in[4];
  const float* Wv = (const float*)d_in[5];
  const float* Wo = (const float*)d_in[6];
  const float* bo = (const float*)d_in[7];
  const float* rel_bias = (const float*)d_in[8];
  const float* fc1_w = (const float*)d_in[9];
  const float* fc1_b = (const float*)d_in[10];
  const float* fc2_w = (const float*)d_in[11];
  const float* fc2_b = (const float*)d_in[12];
  float* out = (float*)d_out;

  const size_t TOKCH = (size_t)NTOK * CH;
  float* ws_f = (float*)d_ws;
  float* yb = ws_f;                            // fp32 y = x + attn-proj (token-major)
  short* wbf    = (short*)(yb + TOKCH);        // bf16 weight pool
  short* tok_bf = wbf + WTOT;                  // (NTOK, 384)
  short* qhm    = tok_bf + TOKCH;              // Q head-major (bh,m,48)
  short* khm    = qhm + HMS;                   // K padded+swizzled (bh,m,64)
  short* vtm    = khm + KHMS;                  // V^T sigma+swizzled (bh,d,SL)
  short* ao_bf  = vtm + HMS;                   // (NTOK, 384)
  short* yb_bf  = ao_bf + TOKCH;               // (NTOK, 384)
  short* h1_bf  = yb_bf + TOKCH;               // (NTOK, 1536)
  // attention partial aliases (dead ranges at attn time):
  short* opw = h1_bf;                          // 2*HMS bf16 <= h1 region
  float* lsw = (float*)tok_bf;                 // 2*NROWS fp32 <= tok region

  k_w2bf<<<WTOT / 8 / 256, 256, 0, stream>>>(Wq, Wk, Wv, Wo, fc1_w, fc2_w, wbf);
  k_ln_fused<<<dim3(SL / 32, BATCH), 256, 0, stream>>>(x, gamma, beta, tok_bf);

  // qkv = tok @ [Wq|Wk|Wv]^T  -> attn-ready q,k,v layouts
  k_gemm_mfma<128, false, false, 0, 8>
      <<<dim3(QKVLD / 128, NTOK / 128), 256, 0, stream>>>(
          tok_bf, wbf + WQKV_OFF, nullptr, nullptr, nullptr, nullptr, nullptr,
          qhm, khm, vtm, QKVLD, CH);

  // split-K attention partials + combine
  k_attn_mfma<<<dim3((SL / 128) * 2, NHEAD, BATCH), 128, 0, stream>>>(
      qhm, khm, vtm, rel_bias, opw, lsw);
  k_attn_combine<<<(NROWS * 6) / 256, 256, 0, stream>>>(opw, lsw, ao_bf);

  // y = x + ao @ Wo^T + bo  (residual from x in (B,C,L)) -> yb fp32 + bf16
  k_gemm_mfma<64, false, true, 2, 3>
      <<<dim3(CH / 128, NTOK / 64), 256, 0, stream>>>(
          ao_bf, wbf + WO_OFF, bo, x, yb, yb_bf, nullptr, nullptr, nullptr,
          nullptr, CH, CH);

  // h1 = gelu(y @ fc1_w^T + fc1_b) -> bf16
  k_gemm_mfma<128, true, true, 0, 2>
      <<<dim3(CFF / 128, NTOK / 128), 256, 0, stream>>>(
          yb_bf, wbf + F1_OFF, fc1_b, nullptr, nullptr, h1_bf, nullptr, nullptr,
          nullptr, nullptr, CFF, CH);

  // out(B,C,L) = y + (h1 @ fc2_w^T + fc2_b)   [direct transposed store]
  k_gemm_mfma<64, false, true, 1, 4>
      <<<dim3(CH / 128, NTOK / 64), 256, 0, stream>>>(
          h1_bf, wbf + F2_OFF, fc2_b, yb, nullptr, nullptr, out, nullptr,
          nullptr, nullptr, CH, CFF);
}

// Round 7
// 205.168 us; speedup vs baseline: 1.0603x; 1.0603x over previous
//
#include <hip/hip_runtime.h>
#include <math.h>

#define SL 1024      // sequence length (H*W)
#define CH 384       // channels
#define NHEAD 8
#define DH 48        // head dim (dk == dv)
#define NBIAS 3969
#define NTOK 8192    // B * SL
#define BATCH 8
#define CFF 1536
#define LN_EPS 1e-5f
#define QKVLD 1152
#define HMS 3145728  // shorts per head-major tensor: B*NH*SL*48
#define LOG2E 1.4426950408889634f

// bf16 weight pool layout (element offsets)
#define WQKV_OFF 0
#define WO_OFF   442368
#define F1_OFF   589824
#define F2_OFF   1179648
#define WTOT     1769472

typedef float floatx4 __attribute__((ext_vector_type(4)));
typedef short bf16x8 __attribute__((ext_vector_type(8)));

__device__ __forceinline__ unsigned f2bf_u(float f) {
  unsigned u = __float_as_uint(f);
  return (u + 0x7fffu + ((u >> 16) & 1u)) >> 16;
}
__device__ __forceinline__ unsigned pack2(float a, float b) {
  return f2bf_u(a) | (f2bf_u(b) << 16);
}
// single-instruction packed f32x2 -> bf16x2 (RNE, same as f2bf_u)
__device__ __forceinline__ unsigned cvtpk(float lo, float hi) {
  unsigned r;
  asm("v_cvt_pk_bf16_f32 %0, %1, %2" : "=v"(r) : "v"(lo), "v"(hi));
  return r;
}

// async global->LDS, 16B per lane; lds base must be wave-uniform
__device__ __forceinline__ void gload_lds16(const void* g, void* l) {
  __builtin_amdgcn_global_load_lds(
      (const __attribute__((address_space(1))) void*)g,
      (__attribute__((address_space(3))) void*)l, 16, 0, 0);
}

// ---------------- weights fp32 -> bf16 pool ----------------
__global__ void k_w2bf(const float* __restrict__ Wq, const float* __restrict__ Wk,
                       const float* __restrict__ Wv, const float* __restrict__ Wo,
                       const float* __restrict__ f1, const float* __restrict__ f2,
                       short* __restrict__ dst) {
  size_t i = ((size_t)blockIdx.x * 256 + threadIdx.x) * 8;
  if (i >= WTOT) return;
  const float* s;
  size_t base;
  if (i < 147456)        { s = Wq; base = 0; }
  else if (i < 294912)   { s = Wk; base = 147456; }
  else if (i < WO_OFF)   { s = Wv; base = 294912; }
  else if (i < F1_OFF)   { s = Wo; base = WO_OFF; }
  else if (i < F2_OFF)   { s = f1; base = F1_OFF; }
  else                   { s = f2; base = F2_OFF; }
  const float4* p = (const float4*)(s + (i - base));
  float4 a = p[0], b = p[1];
  uint4 o;
  o.x = pack2(a.x, a.y); o.y = pack2(a.z, a.w);
  o.z = pack2(b.x, b.y); o.w = pack2(b.z, b.w);
  *(uint4*)(dst + i) = o;
}

// ---------------- fused transpose + LayerNorm: x (B,C,L) -> tok_bf (B*L, C) ----
__global__ __launch_bounds__(256) void k_ln_fused(
    const float* __restrict__ x, const float* __restrict__ gamma,
    const float* __restrict__ beta, short* __restrict__ tok) {
  __shared__ float sx[32][385];  // [l][c]
  int b = blockIdx.y, l0 = blockIdx.x * 32;
  int tid = threadIdx.x;
  const float* xb = x + (size_t)b * CH * SL;
  int cr = tid >> 3, ls = (tid & 7) * 4;
#pragma unroll
  for (int c0 = 0; c0 < CH; c0 += 32) {
    int c = c0 + cr;
    float4 v = *(const float4*)(xb + (size_t)c * SL + l0 + ls);
    sx[ls + 0][c] = v.x; sx[ls + 1][c] = v.y;
    sx[ls + 2][c] = v.z; sx[ls + 3][c] = v.w;
  }
  __syncthreads();
  int tl = tid >> 3, p = tid & 7;  // 8 threads per token, 48 channels each
  float vals[48];
  float s = 0.f, q = 0.f;
#pragma unroll
  for (int i = 0; i < 48; i++) {
    float v = sx[tl][p * 48 + i];
    vals[i] = v; s += v; q += v * v;
  }
  s += __shfl_xor(s, 1, 64); q += __shfl_xor(q, 1, 64);
  s += __shfl_xor(s, 2, 64); q += __shfl_xor(q, 2, 64);
  s += __shfl_xor(s, 4, 64); q += __shfl_xor(q, 4, 64);
  float mu = s * (1.0f / CH);
  float rstd = rsqrtf(q * (1.0f / CH) - mu * mu + LN_EPS);
  short* orow = tok + (size_t)(b * SL + l0 + tl) * CH + p * 48;
#pragma unroll
  for (int i = 0; i < 48; i += 2) {
    float a = (vals[i] - mu) * rstd * gamma[p * 48 + i] + beta[p * 48 + i];
    float c = (vals[i + 1] - mu) * rstd * gamma[p * 48 + i + 1] + beta[p * 48 + i + 1];
    *(unsigned*)(orow + i) = pack2(a, c);
  }
}

// ---------------- bf16 MFMA GEMM: C(M,N) = A(M,K) @ W(N,K)^T ----------------
// Tile BMx128, BK=64. 256 thr = 4 waves 2x2; wave-tile (BM/2)x64.
// RES_MODE: 0 none, 1 row-major fp32, 2 x-layout (B,C,L) fp32.
// OUT_MODE bits: 1 f32 row-major Cf, 2 bf16 Cb, 4 f32 (B,C,L) Ct,
//                8 bf16 head-major qkv split (Chm: q|k|v each HMS shorts).
template <int BM, bool GELU, bool HAS_BIAS, int RES_MODE, int OUT_MODE>
__global__ __launch_bounds__(256) void k_gemm_mfma(
    const short* __restrict__ A, const short* __restrict__ W,
    const float* __restrict__ bias, const float* __restrict__ res,
    float* __restrict__ Cf, short* __restrict__ Cb, float* __restrict__ Ct,
    short* __restrict__ Chm, int N, int K) {
  constexpr int MI = BM / 32;
  constexpr int ASI = BM * 2 / 64;
  __shared__ short As[BM * 64];
  __shared__ short Bs[128 * 64];
  int tid = threadIdx.x;
  int wid = tid >> 6, lane = tid & 63;
  int lanelo = lane & 15, quad = lane >> 4;
  int wm = wid & 1, wn = wid >> 1;
  int m0 = blockIdx.y * BM, n0 = blockIdx.x * 128;

  const short* Aga[ASI];
  short* Ala[ASI];
#pragma unroll
  for (int s = 0; s < ASI; s++) {
    int p = wid * (BM * 2) + s * 64 + lane;
    int row = p >> 3, ch = (p & 7) ^ (row & 7);
    Aga[s] = A + (size_t)(m0 + row) * K + ch * 8;
    Ala[s] = As + (wid * (BM * 2) + s * 64) * 8;
  }
  const short* Bga[4];
  short* Bla[4];
#pragma unroll
  for (int s = 0; s < 4; s++) {
    int p = wid * 256 + s * 64 + lane;
    int row = p >> 3, ch = (p & 7) ^ (row & 7);
    Bga[s] = W + (size_t)(n0 + row) * K + ch * 8;
    Bla[s] = Bs + (wid * 256 + s * 64) * 8;
  }

  floatx4 acc[MI][4];
#pragma unroll
  for (int i = 0; i < MI; i++)
#pragma unroll
    for (int j = 0; j < 4; j++) acc[i][j] = {0.f, 0.f, 0.f, 0.f};

  int x8 = lanelo & 7;
  int ca0 = (quad ^ x8) * 8;
  int ca1 = ((quad + 4) ^ x8) * 8;

  for (int k0 = 0; k0 < K; k0 += 64) {
    __syncthreads();
#pragma unroll
    for (int s = 0; s < ASI; s++) gload_lds16(Aga[s] + k0, Ala[s]);
#pragma unroll
    for (int s = 0; s < 4; s++) gload_lds16(Bga[s] + k0, Bla[s]);
    __syncthreads();
#pragma unroll
    for (int h = 0; h < 2; h++) {
      int co = h ? ca1 : ca0;
      bf16x8 af[MI], bq[4];
#pragma unroll
      for (int i = 0; i < MI; i++)
        af[i] = *(const bf16x8*)&As[(wm * (BM / 2) + i * 16 + lanelo) * 64 + co];
#pragma unroll
      for (int j = 0; j < 4; j++)
        bq[j] = *(const bf16x8*)&Bs[(wn * 64 + j * 16 + lanelo) * 64 + co];
#pragma unroll
      for (int i = 0; i < MI; i++)
#pragma unroll
        for (int j = 0; j < 4; j++)
          acc[i][j] = __builtin_amdgcn_mfma_f32_16x16x32_bf16(af[i], bq[j], acc[i][j], 0, 0, 0);
    }
  }

  // epilogue: C/D row=(lane>>4)*4+reg, col=lane&15; reg = 4 consecutive tokens.
  int colb = n0 + wn * 64 + lanelo;
  float bvv[4];
#pragma unroll
  for (int j = 0; j < 4; j++) bvv[j] = HAS_BIAS ? bias[colb + j * 16] : 0.0f;
#pragma unroll
  for (int i = 0; i < MI; i++) {
    int r = m0 + wm * (BM / 2) + i * 16 + quad * 4;
    int bb = r >> 10, ll = r & 1023;
#pragma unroll
    for (int j = 0; j < 4; j++) {
      int c = colb + j * 16;
      float4 rv = {0.f, 0.f, 0.f, 0.f};
      if (RES_MODE == 2) rv = *(const float4*)(res + ((size_t)bb * CH + c) * SL + ll);
      float vv[4];
#pragma unroll
      for (int reg = 0; reg < 4; reg++) {
        float v = acc[i][j][reg] + bvv[j];
        if (RES_MODE == 1) v += res[(size_t)(r + reg) * N + c];
        if (RES_MODE == 2) v += (&rv.x)[reg];
        if (GELU) v = 0.5f * v * (1.0f + erff(v * 0.7071067811865476f));
        vv[reg] = v;
      }
      if (OUT_MODE & 1) {
#pragma unroll
        for (int reg = 0; reg < 4; reg++) Cf[(size_t)(r + reg) * N + c] = vv[reg];
      }
      if (OUT_MODE & 2) {
#pragma unroll
        for (int reg = 0; reg < 4; reg++) Cb[(size_t)(r + reg) * N + c] = (short)f2bf_u(vv[reg]);
      }
      if (OUT_MODE & 4) {
        float4 ov = {vv[0], vv[1], vv[2], vv[3]};
        *(float4*)(Ct + ((size_t)bb * CH + c) * SL + ll) = ov;
      }
      if (OUT_MODE & 8) {
        int part = c / 384;
        int rem = c - part * 384;
        int hh = rem / 48, dd = rem - hh * 48;
        short* dst = Chm + (size_t)part * HMS +
                     ((size_t)(bb * NHEAD + hh) * SL + ll) * 48 + dd;
#pragma unroll
        for (int reg = 0; reg < 4; reg++) dst[reg * 48] = (short)f2bf_u(vv[reg]);
      }
    }
  }
}

// ---------------- MFMA flash attention, swapped-QK^T, in-register P, ---------
// ---------------- double-buffered K/V staging, VALU-lean softmax ------------
// qh,kh,vh: (B*NH, SL, 48) bf16. ao: (NTOK, 384) bf16 token-major.
// Block: one (b,h), 128 q-rows, 4 waves x 32 rows. m-tiles of 64 keys.
// == round-4 structure (proven 201.4us e2e) + two additive deltas ==
//  (d) bias TABLE: Bt[j] = band[j..j+3]*log2e, 4x-replicated float4 table
//      (1152 entries == exactly the 18.4KB QP alias). Since the bias index
//      is base0 + (nt-qi)*16, 5 aligned ds_read_b128 per lane/tile replace
//      32 scalar ds_read_b32 (the dominant remaining LDS-issue term).
//  (e) T5 s_setprio(1) around the per-tile MFMA/softmax cluster (m191:
//      +4-7% attn in phase-split regime; NOT applied to GEMMs, m190).
// (Round-6 bench was an infra failure -- container died twice during
// acquire; kernel re-audited for bounds/deadlock and resubmitted as-is.)
__global__ __launch_bounds__(256) void k_attn_mfma(
    const short* __restrict__ qh, const short* __restrict__ kh,
    const short* __restrict__ vh, const float* __restrict__ rel_bias,
    short* __restrict__ ao) {
  __shared__ short QP[128 * 72];     // Q (prologue) / bias table (loop) / O^T (epilogue)
  __shared__ short Ks[2][64 * 72];
  __shared__ short Vts[2][48 * 72];  // row=d, col=sigma(k) (PV slot order)
  float4* Bt = (float4*)QP;          // 1152 float4 entries == 18432 B == sizeof(QP)

  int b = blockIdx.z, h = blockIdx.y;
  int l0 = blockIdx.x * 128;
  int tid = threadIdx.x;
  int wid = tid >> 6, lane = tid & 63;
  int lanelo = lane & 15, quad = lane >> 4;
  size_t hb = ((size_t)b * NHEAD + h) * SL;
  size_t bSL = (size_t)b * SL;
  const short* kbase = kh + hb * 48;
  const short* vbase = vh + hb * 48;

  // ---- stage Q tile (contiguous 12 KB, 768 granules, 3/thread) ----
  {
    const short* qsrc = qh + (hb + l0) * 48;
#pragma unroll
    for (int s = 0; s < 3; s++) {
      int g = tid + 256 * s;
      int row = g / 6, pos = g - row * 6;
      *(uint4*)&QP[row * 72 + pos * 8] = *(const uint4*)(qsrc + g * 8);
    }
  }
  // zero pads (Q 128 rows, both K buffers 64 rows; cols 48..63)
  for (int z = tid; z < 128 * 8; z += 256) {
    int r = z >> 3, u = z & 7;
    ((unsigned*)&QP[r * 72 + 48])[u] = 0u;
    if (r < 64) {
      ((unsigned*)&Ks[0][r * 72 + 48])[u] = 0u;
      ((unsigned*)&Ks[1][r * 72 + 48])[u] = 0u;
    }
  }
  __syncthreads();

  // resident Q B-fragments: [qi][chalf] (lane holds Q[q=lanelo][c=quad*8+j])
  bf16x8 aq[2][2];
#pragma unroll
  for (int qi = 0; qi < 2; qi++) {
    aq[qi][0] = *(const bf16x8*)&QP[(wid * 32 + qi * 16 + lanelo) * 72 + quad * 8];
    aq[qi][1] = *(const bf16x8*)&QP[(wid * 32 + qi * 16 + lanelo) * 72 + 32 + quad * 8];
  }
  __syncthreads();  // aq consumed; QP region may be overwritten by bias table

  // staging assignment (tid<192): K granule pair kg=2*tid; V token-pair+d-group
  int kg = 2 * tid;
  int krow = kg / 6, kpos = kg - krow * 6;  // kg even -> kpos in {0,2,4}
  int vmp = tid & 31, vdg = tid >> 5;
  // V column permutation sigma(k): k = g*32+s*16+Q*4+r -> col = g*32+Q*8+s*4+r
  int kk = 2 * vmp;
  int vcol = (kk & 3) + ((kk >> 2) & 3) * 8 + ((kk >> 4) & 1) * 4 + (kk >> 5) * 32;
  unsigned sel_e = 0x05040100u, sel_o = 0x07060302u;  // v_perm selectors

  // ---- build 4x-replicated bias table into QP alias ----
  // Bt[j] = band[j..j+3] * log2e; band[j] = rel_bias[h*NBIAS + 929-l0 + j].
  // Max source index: 929-l0+1154 <= 2083 < NBIAS (in-row); used range <= 1150.
  {
    const float* bsrc = rel_bias + h * NBIAS + (929 - l0);
    for (int j = tid; j < 1152; j += 256) {
      float4 t;
      t.x = bsrc[j] * LOG2E;     t.y = bsrc[j + 1] * LOG2E;
      t.z = bsrc[j + 2] * LOG2E; t.w = bsrc[j + 3] * LOG2E;
      Bt[j] = t;
    }
  }
  // ---- stage K/V tile 0 into buffer 0 ----
  if (tid < 192) {
    const short* ksrc = kbase + kg * 8;
    uint4 k0 = *(const uint4*)(ksrc);
    uint4 k1 = *(const uint4*)(ksrc + 8);
    const short* vs = vbase + (size_t)kk * 48 + vdg * 8;
    uint4 va = *(const uint4*)vs;
    uint4 vb = *(const uint4*)(vs + 48);
    *(uint4*)&Ks[0][krow * 72 + kpos * 8] = k0;
    *(uint4*)&Ks[0][krow * 72 + (kpos + 1) * 8] = k1;
#pragma unroll
    for (int j = 0; j < 4; j++) {
      unsigned wa = ((const unsigned*)&va)[j], wb = ((const unsigned*)&vb)[j];
      unsigned pe, po;
      asm("v_perm_b32 %0, %1, %2, %3" : "=v"(pe) : "v"(wb), "v"(wa), "v"(sel_e));
      asm("v_perm_b32 %0, %1, %2, %3" : "=v"(po) : "v"(wb), "v"(wa), "v"(sel_o));
      *(unsigned*)&Vts[0][(vdg * 8 + 2 * j + 0) * 72 + vcol] = pe;
      *(unsigned*)&Vts[0][(vdg * 8 + 2 * j + 1) * 72 + vcol] = po;
    }
  }
  __syncthreads();

  floatx4 O[3][2];  // O^T accum: [dt][qi], C-layout row=d=quad*4+reg, col=q=lanelo
#pragma unroll
  for (int dt = 0; dt < 3; dt++)
#pragma unroll
    for (int qi = 0; qi < 2; qi++) O[dt][qi] = {0.f, 0.f, 0.f, 0.f};
  float lsum[2] = {0.f, 0.f};
  // bias table index: Bt[base0 + mt + (nt-qi)*16] = band[bidx..bidx+3]
  int base00 = 127 + quad * 4 - wid * 32 - lanelo;

  int cur = 0;
  for (int mt = 0; mt < SL; mt += 64) {
    bool last = (mt + 64 >= SL);
    int mtn = last ? 0 : mt + 64;  // dummy reload of tile 0 on last iter
    uint4 k0n, k1n, van, vbn;
    if (tid < 192) {  // issue next-tile global loads EARLY (latency under compute)
      const short* ksrc = kbase + (size_t)mtn * 48 + kg * 8;
      k0n = *(const uint4*)(ksrc);
      k1n = *(const uint4*)(ksrc + 8);
      const short* vs = vbase + (size_t)(mtn + kk) * 48 + vdg * 8;
      van = *(const uint4*)vs;
      vbn = *(const uint4*)(vs + 48);
    }

    // ---- compute tile from buffer cur ----
    // K A-fragments (lane holds K[k=nt*16+lanelo][c=quad*8+j])
    bf16x8 kb[4][2];
#pragma unroll
    for (int nt = 0; nt < 4; nt++) {
      kb[nt][0] = *(const bf16x8*)&Ks[cur][(nt * 16 + lanelo) * 72 + quad * 8];
      kb[nt][1] = *(const bf16x8*)&Ks[cur][(nt * 16 + lanelo) * 72 + 32 + quad * 8];
    }
    // V^T A-fragments (lane holds V^T[d=dt*16+lanelo][slot g*32+quad*8+j])
    bf16x8 vf[3][2];
#pragma unroll
    for (int dt = 0; dt < 3; dt++) {
      vf[dt][0] = *(const bf16x8*)&Vts[cur][(dt * 16 + lanelo) * 72 + quad * 8];
      vf[dt][1] = *(const bf16x8*)&Vts[cur][(dt * 16 + lanelo) * 72 + 32 + quad * 8];
    }
    // bias: 5 shared float4 rows cover all 8 (qi,nt) pairs (index nt-qi+1)
    float4 bvt[5];
    int b0 = base00 + mt;
#pragma unroll
    for (int t = 0; t < 5; t++) bvt[t] = Bt[b0 + (t - 1) * 16];

    __builtin_amdgcn_s_setprio(1);
#pragma unroll
    for (int qi = 0; qi < 2; qi++) {
      // S^T = K @ Q^T: C row=k=quad*4+reg(+nt*16), col=q=lanelo
      floatx4 sc[4];
#pragma unroll
      for (int nt = 0; nt < 4; nt++) {
        floatx4 a = {0.f, 0.f, 0.f, 0.f};
        a = __builtin_amdgcn_mfma_f32_16x16x32_bf16(kb[nt][0], aq[qi][0], a, 0, 0, 0);
        a = __builtin_amdgcn_mfma_f32_16x16x32_bf16(kb[nt][1], aq[qi][1], a, 0, 0, 0);
        sc[nt] = a;
      }
      // softmax (no running max: scores bounded), pack in-register via cvt_pk
      union U8 { unsigned u[4]; bf16x8 v; };
      U8 pb0, pb1;
#pragma unroll
      for (int nt = 0; nt < 4; nt++) {
        float4 bb = bvt[nt - qi + 1];
        float e0 = __builtin_amdgcn_exp2f(fmaf(sc[nt][0], LOG2E, bb.x));
        float e1 = __builtin_amdgcn_exp2f(fmaf(sc[nt][1], LOG2E, bb.y));
        float e2 = __builtin_amdgcn_exp2f(fmaf(sc[nt][2], LOG2E, bb.z));
        float e3 = __builtin_amdgcn_exp2f(fmaf(sc[nt][3], LOG2E, bb.w));
        lsum[qi] += (e0 + e1) + (e2 + e3);
        unsigned p01 = cvtpk(e0, e1), p23 = cvtpk(e2, e3);
        if (nt == 0) { pb0.u[0] = p01; pb0.u[1] = p23; }
        else if (nt == 1) { pb0.u[2] = p01; pb0.u[3] = p23; }
        else if (nt == 2) { pb1.u[0] = p01; pb1.u[1] = p23; }
        else { pb1.u[2] = p01; pb1.u[3] = p23; }
      }
      // lane's own packed scores ARE the PV B-fragment (V k-axis permuted)
#pragma unroll
      for (int dt = 0; dt < 3; dt++) {
        O[dt][qi] = __builtin_amdgcn_mfma_f32_16x16x32_bf16(vf[dt][0], pb0.v, O[dt][qi], 0, 0, 0);
        O[dt][qi] = __builtin_amdgcn_mfma_f32_16x16x32_bf16(vf[dt][1], pb1.v, O[dt][qi], 0, 0, 0);
      }
    }
    __builtin_amdgcn_s_setprio(0);

    // ---- write next tile into the other buffer (loads drained here) ----
    if (tid < 192 && !last) {
      int nxt = cur ^ 1;
      *(uint4*)&Ks[nxt][krow * 72 + kpos * 8] = k0n;
      *(uint4*)&Ks[nxt][krow * 72 + (kpos + 1) * 8] = k1n;
#pragma unroll
      for (int j = 0; j < 4; j++) {
        unsigned wa = ((const unsigned*)&van)[j], wb = ((const unsigned*)&vbn)[j];
        unsigned pe, po;
        asm("v_perm_b32 %0, %1, %2, %3" : "=v"(pe) : "v"(wb), "v"(wa), "v"(sel_e));
        asm("v_perm_b32 %0, %1, %2, %3" : "=v"(po) : "v"(wb), "v"(wa), "v"(sel_o));
        *(unsigned*)&Vts[nxt][(vdg * 8 + 2 * j + 0) * 72 + vcol] = pe;
        *(unsigned*)&Vts[nxt][(vdg * 8 + 2 * j + 1) * 72 + vcol] = po;
      }
    }
    __syncthreads();
    cur ^= 1;
  }

  // ---- epilogue: reduce denom over quads, normalize, transpose O^T via QP ----
  __syncthreads();  // all waves done reading Bt (aliases QP)
  float inv[2];
#pragma unroll
  for (int qi = 0; qi < 2; qi++) {
    float s = lsum[qi];
    s += __shfl_xor(s, 16, 64);
    s += __shfl_xor(s, 32, 64);
    inv[qi] = __builtin_amdgcn_rcpf(s);
  }
  // wave-local: write O^T (d-adjacent regs packed) into this wave's QP rows [q][d]
#pragma unroll
  for (int dt = 0; dt < 3; dt++)
#pragma unroll
    for (int qi = 0; qi < 2; qi++) {
      unsigned w0 = cvtpk(O[dt][qi][0] * inv[qi], O[dt][qi][1] * inv[qi]);
      unsigned w1 = cvtpk(O[dt][qi][2] * inv[qi], O[dt][qi][3] * inv[qi]);
      uint2 wv = {w0, w1};
      *(uint2*)&QP[(wid * 32 + qi * 16 + lanelo) * 72 + dt * 16 + quad * 4] = wv;
    }
  __asm__ volatile("s_waitcnt lgkmcnt(0)" ::: "memory");  // wave-local transpose
  // read back 16B granules, coalesced global store
#pragma unroll
  for (int s = 0; s < 3; s++) {
    int g = lane + 64 * s;  // 0..191: 32 rows x 6 granules
    int qloc = g / 6, pos = g - qloc * 6;
    uint4 val = *(const uint4*)&QP[(wid * 32 + qloc) * 72 + pos * 8];
    *(uint4*)(ao + (bSL + (size_t)(l0 + wid * 32 + qloc)) * CH + h * DH + pos * 8) = val;
  }
}

// ---------------- launch ----------------
extern "C" void kernel_launch(void* const* d_in, const int* in_sizes, int n_in,
                              void* d_out, int out_size, void* d_ws, size_t ws_size,
                              hipStream_t stream) {
  const float* x = (const float*)d_in[0];
  const float* gamma = (const float*)d_in[1];
  const float* beta = (const float*)d_in[2];
  const float* Wq = (const float*)d_in[3];
  const float* Wk = (const float*)d_in[4];
  const float* Wv = (const float*)d_in[5];
  const float* Wo = (const float*)d_in[6];
  const float* bo = (const float*)d_in[7];
  const float* rel_bias = (const float*)d_in[8];
  const float* fc1_w = (const float*)d_in[9];
  const float* fc1_b = (const float*)d_in[10];
  const float* fc2_w = (const float*)d_in[11];
  const float* fc2_b = (const float*)d_in[12];
  float* out = (float*)d_out;

  const size_t TOKCH = (size_t)NTOK * CH;
  float* ws_f = (float*)d_ws;
  float* yb = ws_f;                            // fp32 y = x + attn-proj (token-major)
  short* wbf    = (short*)(yb + TOKCH);        // bf16 weight pool
  short* tok_bf = wbf + WTOT;                  // (NTOK, 384)
  short* hm     = tok_bf + TOKCH;              // q|k|v head-major, 3*HMS shorts
  short* ao_bf  = hm + 3 * (size_t)HMS;        // (NTOK, 384)
  short* yb_bf  = ao_bf + TOKCH;               // (NTOK, 384)
  short* h1_bf  = yb_bf + TOKCH;               // (NTOK, 1536)

  k_w2bf<<<WTOT / 8 / 256, 256, 0, stream>>>(Wq, Wk, Wv, Wo, fc1_w, fc2_w, wbf);
  k_ln_fused<<<dim3(SL / 32, BATCH), 256, 0, stream>>>(x, gamma, beta, tok_bf);

  // qkv = tok @ [Wq|Wk|Wv]^T  -> head-major q,k,v
  k_gemm_mfma<128, false, false, 0, 8>
      <<<dim3(QKVLD / 128, NTOK / 128), 256, 0, stream>>>(
          tok_bf, wbf + WQKV_OFF, nullptr, nullptr, nullptr, nullptr, nullptr,
          hm, QKVLD, CH);

  k_attn_mfma<<<dim3(SL / 128, NHEAD, BATCH), 256, 0, stream>>>(
      hm, hm + HMS, hm + 2 * (size_t)HMS, rel_bias, ao_bf);

  // y = x + ao @ Wo^T + bo  (residual from x in (B,C,L)) -> yb fp32 + bf16
  k_gemm_mfma<64, false, true, 2, 3>
      <<<dim3(CH / 128, NTOK / 64), 256, 0, stream>>>(
          ao_bf, wbf + WO_OFF, bo, x, yb, yb_bf, nullptr, nullptr, CH, CH);

  // h1 = gelu(y @ fc1_w^T + fc1_b) -> bf16
  k_gemm_mfma<128, true, true, 0, 2>
      <<<dim3(CFF / 128, NTOK / 128), 256, 0, stream>>>(
          yb_bf, wbf + F1_OFF, fc1_b, nullptr, nullptr, h1_bf, nullptr, nullptr,
          CFF, CH);

  // out(B,C,L) = y + (h1 @ fc2_w^T + fc2_b)   [direct transposed store]
  k_gemm_mfma<64, false, true, 1, 4>
      <<<dim3(CH / 128, NTOK / 64), 256, 0, stream>>>(
          h1_bf, wbf + F2_OFF, fc2_b, yb, nullptr, nullptr, out, nullptr, CH, CFF);
}

// Round 8
// 194.694 us; speedup vs baseline: 1.1173x; 1.0538x over previous
//
#include <hip/hip_runtime.h>
#include <math.h>

#define SL 1024      // sequence length (H*W)
#define CH 384       // channels
#define NHEAD 8
#define DH 48        // head dim (dk == dv)
#define NBIAS 3969
#define NTOK 8192    // B * SL
#define BATCH 8
#define CFF 1536
#define LN_EPS 1e-5f
#define QKVLD 1152
#define HMS 3145728  // shorts per head-major tensor: B*NH*SL*48
#define LOG2E 1.4426950408889634f

// bf16 weight pool layout (element offsets)
#define WQKV_OFF 0
#define WO_OFF   442368
#define F1_OFF   589824
#define F2_OFF   1179648
#define WTOT     1769472

typedef float floatx4 __attribute__((ext_vector_type(4)));
typedef short bf16x8 __attribute__((ext_vector_type(8)));

__device__ __forceinline__ unsigned f2bf_u(float f) {
  unsigned u = __float_as_uint(f);
  return (u + 0x7fffu + ((u >> 16) & 1u)) >> 16;
}
__device__ __forceinline__ unsigned pack2(float a, float b) {
  return f2bf_u(a) | (f2bf_u(b) << 16);
}
// single-instruction packed f32x2 -> bf16x2 (RNE, same as f2bf_u)
__device__ __forceinline__ unsigned cvtpk(float lo, float hi) {
  unsigned r;
  asm("v_cvt_pk_bf16_f32 %0, %1, %2" : "=v"(r) : "v"(lo), "v"(hi));
  return r;
}

// async global->LDS, 16B per lane; lds base must be wave-uniform
__device__ __forceinline__ void gload_lds16(const void* g, void* l) {
  __builtin_amdgcn_global_load_lds(
      (const __attribute__((address_space(1))) void*)g,
      (__attribute__((address_space(3))) void*)l, 16, 0, 0);
}

// ---------------- weights fp32 -> bf16 pool ----------------
__global__ void k_w2bf(const float* __restrict__ Wq, const float* __restrict__ Wk,
                       const float* __restrict__ Wv, const float* __restrict__ Wo,
                       const float* __restrict__ f1, const float* __restrict__ f2,
                       short* __restrict__ dst) {
  size_t i = ((size_t)blockIdx.x * 256 + threadIdx.x) * 8;
  if (i >= WTOT) return;
  const float* s;
  size_t base;
  if (i < 147456)        { s = Wq; base = 0; }
  else if (i < 294912)   { s = Wk; base = 147456; }
  else if (i < WO_OFF)   { s = Wv; base = 294912; }
  else if (i < F1_OFF)   { s = Wo; base = WO_OFF; }
  else if (i < F2_OFF)   { s = f1; base = F1_OFF; }
  else                   { s = f2; base = F2_OFF; }
  const float4* p = (const float4*)(s + (i - base));
  float4 a = p[0], b = p[1];
  uint4 o;
  o.x = pack2(a.x, a.y); o.y = pack2(a.z, a.w);
  o.z = pack2(b.x, b.y); o.w = pack2(b.z, b.w);
  *(uint4*)(dst + i) = o;
}

// ---------------- fused transpose + LayerNorm: x (B,C,L) -> tok_bf (B*L, C) ----
__global__ __launch_bounds__(256) void k_ln_fused(
    const float* __restrict__ x, const float* __restrict__ gamma,
    const float* __restrict__ beta, short* __restrict__ tok) {
  __shared__ float sx[32][385];  // [l][c]
  int b = blockIdx.y, l0 = blockIdx.x * 32;
  int tid = threadIdx.x;
  const float* xb = x + (size_t)b * CH * SL;
  int cr = tid >> 3, ls = (tid & 7) * 4;
#pragma unroll
  for (int c0 = 0; c0 < CH; c0 += 32) {
    int c = c0 + cr;
    float4 v = *(const float4*)(xb + (size_t)c * SL + l0 + ls);
    sx[ls + 0][c] = v.x; sx[ls + 1][c] = v.y;
    sx[ls + 2][c] = v.z; sx[ls + 3][c] = v.w;
  }
  __syncthreads();
  int tl = tid >> 3, p = tid & 7;  // 8 threads per token, 48 channels each
  float vals[48];
  float s = 0.f, q = 0.f;
#pragma unroll
  for (int i = 0; i < 48; i++) {
    float v = sx[tl][p * 48 + i];
    vals[i] = v; s += v; q += v * v;
  }
  s += __shfl_xor(s, 1, 64); q += __shfl_xor(q, 1, 64);
  s += __shfl_xor(s, 2, 64); q += __shfl_xor(q, 2, 64);
  s += __shfl_xor(s, 4, 64); q += __shfl_xor(q, 4, 64);
  float mu = s * (1.0f / CH);
  float rstd = rsqrtf(q * (1.0f / CH) - mu * mu + LN_EPS);
  short* orow = tok + (size_t)(b * SL + l0 + tl) * CH + p * 48;
#pragma unroll
  for (int i = 0; i < 48; i += 2) {
    float a = (vals[i] - mu) * rstd * gamma[p * 48 + i] + beta[p * 48 + i];
    float c = (vals[i + 1] - mu) * rstd * gamma[p * 48 + i + 1] + beta[p * 48 + i + 1];
    *(unsigned*)(orow + i) = pack2(a, c);
  }
}

// ---------------- bf16 MFMA GEMM: C(M,N) = A(M,K) @ W(N,K)^T ----------------
// Tile BMx128, BK=64. 256 thr = 4 waves 2x2; wave-tile (BM/2)x64.
// RES_MODE: 0 none, 1 row-major fp32, 2 x-layout (B,C,L) fp32.
// OUT_MODE bits: 1 f32 row-major Cf, 2 bf16 Cb, 4 f32 (B,C,L) Ct,
//                8 bf16 head-major qkv split (Chm: q|k|v each HMS shorts).
// T1 XCD swizzle: all launches have gridX*gridY divisible by 8; XCD k
// processes a contiguous chunk of the linearized grid (A-panel + B-panel
// working set per chunk < 4MB XCD L2).
template <int BM, bool GELU, bool HAS_BIAS, int RES_MODE, int OUT_MODE>
__global__ __launch_bounds__(256) void k_gemm_mfma(
    const short* __restrict__ A, const short* __restrict__ W,
    const float* __restrict__ bias, const float* __restrict__ res,
    float* __restrict__ Cf, short* __restrict__ Cb, float* __restrict__ Ct,
    short* __restrict__ Chm, int N, int K) {
  constexpr int MI = BM / 32;
  constexpr int ASI = BM * 2 / 64;
  __shared__ short As[BM * 64];
  __shared__ short Bs[128 * 64];
  int tid = threadIdx.x;
  int wid = tid >> 6, lane = tid & 63;
  int lanelo = lane & 15, quad = lane >> 4;
  int wm = wid & 1, wn = wid >> 1;

  // XCD-chunked bijective swizzle (nwg % 8 == 0 for all launches)
  int nbx = (int)gridDim.x;
  int lin = (int)blockIdx.y * nbx + (int)blockIdx.x;
  int chunk = (nbx * (int)gridDim.y) >> 3;
  int wk = (lin & 7) * chunk + (lin >> 3);
  int m0 = (wk / nbx) * BM, n0 = (wk % nbx) * 128;

  const short* Aga[ASI];
  short* Ala[ASI];
#pragma unroll
  for (int s = 0; s < ASI; s++) {
    int p = wid * (BM * 2) + s * 64 + lane;
    int row = p >> 3, ch = (p & 7) ^ (row & 7);
    Aga[s] = A + (size_t)(m0 + row) * K + ch * 8;
    Ala[s] = As + (wid * (BM * 2) + s * 64) * 8;
  }
  const short* Bga[4];
  short* Bla[4];
#pragma unroll
  for (int s = 0; s < 4; s++) {
    int p = wid * 256 + s * 64 + lane;
    int row = p >> 3, ch = (p & 7) ^ (row & 7);
    Bga[s] = W + (size_t)(n0 + row) * K + ch * 8;
    Bla[s] = Bs + (wid * 256 + s * 64) * 8;
  }

  floatx4 acc[MI][4];
#pragma unroll
  for (int i = 0; i < MI; i++)
#pragma unroll
    for (int j = 0; j < 4; j++) acc[i][j] = {0.f, 0.f, 0.f, 0.f};

  int x8 = lanelo & 7;
  int ca0 = (quad ^ x8) * 8;
  int ca1 = ((quad + 4) ^ x8) * 8;

  for (int k0 = 0; k0 < K; k0 += 64) {
    __syncthreads();
#pragma unroll
    for (int s = 0; s < ASI; s++) gload_lds16(Aga[s] + k0, Ala[s]);
#pragma unroll
    for (int s = 0; s < 4; s++) gload_lds16(Bga[s] + k0, Bla[s]);
    __syncthreads();
#pragma unroll
    for (int h = 0; h < 2; h++) {
      int co = h ? ca1 : ca0;
      bf16x8 af[MI], bq[4];
#pragma unroll
      for (int i = 0; i < MI; i++)
        af[i] = *(const bf16x8*)&As[(wm * (BM / 2) + i * 16 + lanelo) * 64 + co];
#pragma unroll
      for (int j = 0; j < 4; j++)
        bq[j] = *(const bf16x8*)&Bs[(wn * 64 + j * 16 + lanelo) * 64 + co];
#pragma unroll
      for (int i = 0; i < MI; i++)
#pragma unroll
        for (int j = 0; j < 4; j++)
          acc[i][j] = __builtin_amdgcn_mfma_f32_16x16x32_bf16(af[i], bq[j], acc[i][j], 0, 0, 0);
    }
  }

  // epilogue: C/D row=(lane>>4)*4+reg, col=lane&15; reg = 4 consecutive tokens.
  int colb = n0 + wn * 64 + lanelo;
  float bvv[4];
#pragma unroll
  for (int j = 0; j < 4; j++) bvv[j] = HAS_BIAS ? bias[colb + j * 16] : 0.0f;
#pragma unroll
  for (int i = 0; i < MI; i++) {
    int r = m0 + wm * (BM / 2) + i * 16 + quad * 4;
    int bb = r >> 10, ll = r & 1023;
#pragma unroll
    for (int j = 0; j < 4; j++) {
      int c = colb + j * 16;
      float4 rv = {0.f, 0.f, 0.f, 0.f};
      if (RES_MODE == 2) rv = *(const float4*)(res + ((size_t)bb * CH + c) * SL + ll);
      float vv[4];
#pragma unroll
      for (int reg = 0; reg < 4; reg++) {
        float v = acc[i][j][reg] + bvv[j];
        if (RES_MODE == 1) v += res[(size_t)(r + reg) * N + c];
        if (RES_MODE == 2) v += (&rv.x)[reg];
        if (GELU) v = 0.5f * v * (1.0f + erff(v * 0.7071067811865476f));
        vv[reg] = v;
      }
      if (OUT_MODE & 1) {
#pragma unroll
        for (int reg = 0; reg < 4; reg++) Cf[(size_t)(r + reg) * N + c] = vv[reg];
      }
      if (OUT_MODE & 2) {
#pragma unroll
        for (int reg = 0; reg < 4; reg++) Cb[(size_t)(r + reg) * N + c] = (short)f2bf_u(vv[reg]);
      }
      if (OUT_MODE & 4) {
        float4 ov = {vv[0], vv[1], vv[2], vv[3]};
        *(float4*)(Ct + ((size_t)bb * CH + c) * SL + ll) = ov;
      }
      if (OUT_MODE & 8) {
        int part = c / 384;
        int rem = c - part * 384;
        int hh = rem / 48, dd = rem - hh * 48;
        short* dst = Chm + (size_t)part * HMS +
                     ((size_t)(bb * NHEAD + hh) * SL + ll) * 48 + dd;
#pragma unroll
        for (int reg = 0; reg < 4; reg++) dst[reg * 48] = (short)f2bf_u(vv[reg]);
      }
    }
  }
}

// ---------------- MFMA flash attention, swapped-QK^T, in-register P, ---------
// ---------------- double-buffered K/V staging, VALU-lean softmax ------------
// == EXACT round-4 structure (best measured: 201.4us e2e) + T1 XCD swizzle ==
// (round-7's bias-table + setprio deltas measured neutral-to-negative ->
// reverted; setprio was the m190-null regime: 4-wave barrier-synced loop.)
// Swizzle: grid (8,8,8) linearized = b*64+h*8+lt; XCD k gets 64 consecutive
// work ids = one full batch (8 heads x 8 q-tiles; K/V set 1.6MB < L2).
__global__ __launch_bounds__(256) void k_attn_mfma(
    const short* __restrict__ qh, const short* __restrict__ kh,
    const short* __restrict__ vh, const float* __restrict__ rel_bias,
    short* __restrict__ ao) {
  __shared__ short QP[128 * 72];     // Q (prologue) / bias band (loop) / O^T (epilogue)
  __shared__ short Ks[2][64 * 72];
  __shared__ short Vts[2][48 * 72];  // row=d, col=sigma(k) (PV slot order)
  float* Bb = (float*)QP;            // 1152 floats, aliases QP rows 0..31

  int lin = ((int)blockIdx.z * 8 + (int)blockIdx.y) * 8 + (int)blockIdx.x;
  int wk = (lin & 7) * 64 + (lin >> 3);
  int b = wk >> 6, h = (wk >> 3) & 7;
  int l0 = (wk & 7) * 128;
  int tid = threadIdx.x;
  int wid = tid >> 6, lane = tid & 63;
  int lanelo = lane & 15, quad = lane >> 4;
  size_t hb = ((size_t)b * NHEAD + h) * SL;
  size_t bSL = (size_t)b * SL;
  const short* kbase = kh + hb * 48;
  const short* vbase = vh + hb * 48;

  // ---- stage Q tile (contiguous 12 KB, 768 granules, 3/thread) ----
  {
    const short* qsrc = qh + (hb + l0) * 48;
#pragma unroll
    for (int s = 0; s < 3; s++) {
      int g = tid + 256 * s;
      int row = g / 6, pos = g - row * 6;
      *(uint4*)&QP[row * 72 + pos * 8] = *(const uint4*)(qsrc + g * 8);
    }
  }
  // zero pads (Q 128 rows, both K buffers 64 rows; cols 48..63)
  for (int z = tid; z < 128 * 8; z += 256) {
    int r = z >> 3, u = z & 7;
    ((unsigned*)&QP[r * 72 + 48])[u] = 0u;
    if (r < 64) {
      ((unsigned*)&Ks[0][r * 72 + 48])[u] = 0u;
      ((unsigned*)&Ks[1][r * 72 + 48])[u] = 0u;
    }
  }
  __syncthreads();

  // resident Q B-fragments: [qi][chalf] (lane holds Q[q=lanelo][c=quad*8+j])
  bf16x8 aq[2][2];
#pragma unroll
  for (int qi = 0; qi < 2; qi++) {
    aq[qi][0] = *(const bf16x8*)&QP[(wid * 32 + qi * 16 + lanelo) * 72 + quad * 8];
    aq[qi][1] = *(const bf16x8*)&QP[(wid * 32 + qi * 16 + lanelo) * 72 + 32 + quad * 8];
  }
  __syncthreads();  // aq consumed; QP region may be overwritten by bias band

  // staging assignment (tid<192): K granule pair kg=2*tid; V token-pair+d-group
  int kg = 2 * tid;
  int krow = kg / 6, kpos = kg - krow * 6;  // kg even -> kpos in {0,2,4}
  int vmp = tid & 31, vdg = tid >> 5;
  // V column permutation sigma(k): k = g*32+s*16+Q*4+r -> col = g*32+Q*8+s*4+r
  int kk = 2 * vmp;
  int vcol = (kk & 3) + ((kk >> 2) & 3) * 8 + ((kk >> 4) & 1) * 4 + (kk >> 5) * 32;
  unsigned sel_e = 0x05040100u, sel_o = 0x07060302u;  // v_perm selectors

  // ---- stage bias band (pre-scaled by log2e) into QP alias ----
  {
    const float* bsrc = rel_bias + h * NBIAS + (929 - l0);
    for (int j = tid; j < 1152; j += 256) Bb[j] = bsrc[j] * LOG2E;
  }
  // ---- stage K/V tile 0 into buffer 0 ----
  if (tid < 192) {
    const short* ksrc = kbase + kg * 8;
    uint4 k0 = *(const uint4*)(ksrc);
    uint4 k1 = *(const uint4*)(ksrc + 8);
    const short* vs = vbase + (size_t)kk * 48 + vdg * 8;
    uint4 va = *(const uint4*)vs;
    uint4 vb = *(const uint4*)(vs + 48);
    *(uint4*)&Ks[0][krow * 72 + kpos * 8] = k0;
    *(uint4*)&Ks[0][krow * 72 + (kpos + 1) * 8] = k1;
#pragma unroll
    for (int j = 0; j < 4; j++) {
      unsigned wa = ((const unsigned*)&va)[j], wb = ((const unsigned*)&vb)[j];
      unsigned pe, po;
      asm("v_perm_b32 %0, %1, %2, %3" : "=v"(pe) : "v"(wb), "v"(wa), "v"(sel_e));
      asm("v_perm_b32 %0, %1, %2, %3" : "=v"(po) : "v"(wb), "v"(wa), "v"(sel_o));
      *(unsigned*)&Vts[0][(vdg * 8 + 2 * j + 0) * 72 + vcol] = pe;
      *(unsigned*)&Vts[0][(vdg * 8 + 2 * j + 1) * 72 + vcol] = po;
    }
  }
  __syncthreads();

  floatx4 O[3][2];  // O^T accum: [dt][qi], C-layout row=d=quad*4+reg, col=q=lanelo
#pragma unroll
  for (int dt = 0; dt < 3; dt++)
#pragma unroll
    for (int qi = 0; qi < 2; qi++) O[dt][qi] = {0.f, 0.f, 0.f, 0.f};
  float lsum[2] = {0.f, 0.f};
  // bias LDS offset: j = k - (l - l0) + 127; k = mt + nt*16 + quad*4 + reg
  int boff[2];
#pragma unroll
  for (int qi = 0; qi < 2; qi++)
    boff[qi] = 127 + quad * 4 - (wid * 32 + qi * 16 + lanelo);

  int cur = 0;
  for (int mt = 0; mt < SL; mt += 64) {
    bool last = (mt + 64 >= SL);
    int mtn = last ? 0 : mt + 64;  // dummy reload of tile 0 on last iter
    uint4 k0n, k1n, van, vbn;
    if (tid < 192) {  // issue next-tile global loads EARLY (latency under compute)
      const short* ksrc = kbase + (size_t)mtn * 48 + kg * 8;
      k0n = *(const uint4*)(ksrc);
      k1n = *(const uint4*)(ksrc + 8);
      const short* vs = vbase + (size_t)(mtn + kk) * 48 + vdg * 8;
      van = *(const uint4*)vs;
      vbn = *(const uint4*)(vs + 48);
    }

    // ---- compute tile from buffer cur ----
    // K A-fragments (lane holds K[k=nt*16+lanelo][c=quad*8+j])
    bf16x8 kb[4][2];
#pragma unroll
    for (int nt = 0; nt < 4; nt++) {
      kb[nt][0] = *(const bf16x8*)&Ks[cur][(nt * 16 + lanelo) * 72 + quad * 8];
      kb[nt][1] = *(const bf16x8*)&Ks[cur][(nt * 16 + lanelo) * 72 + 32 + quad * 8];
    }
    // V^T A-fragments (lane holds V^T[d=dt*16+lanelo][slot g*32+quad*8+j])
    bf16x8 vf[3][2];
#pragma unroll
    for (int dt = 0; dt < 3; dt++) {
      vf[dt][0] = *(const bf16x8*)&Vts[cur][(dt * 16 + lanelo) * 72 + quad * 8];
      vf[dt][1] = *(const bf16x8*)&Vts[cur][(dt * 16 + lanelo) * 72 + 32 + quad * 8];
    }

#pragma unroll
    for (int qi = 0; qi < 2; qi++) {
      // S^T = K @ Q^T: C row=k=quad*4+reg(+nt*16), col=q=lanelo
      floatx4 sc[4];
#pragma unroll
      for (int nt = 0; nt < 4; nt++) {
        floatx4 a = {0.f, 0.f, 0.f, 0.f};
        a = __builtin_amdgcn_mfma_f32_16x16x32_bf16(kb[nt][0], aq[qi][0], a, 0, 0, 0);
        a = __builtin_amdgcn_mfma_f32_16x16x32_bf16(kb[nt][1], aq[qi][1], a, 0, 0, 0);
        sc[nt] = a;
      }
      // softmax (no running max: scores bounded), pack in-register via cvt_pk
      union U8 { unsigned u[4]; bf16x8 v; };
      U8 pb0, pb1;
#pragma unroll
      for (int nt = 0; nt < 4; nt++) {
        int bidx = boff[qi] + mt + nt * 16;
        float e0 = __builtin_amdgcn_exp2f(fmaf(sc[nt][0], LOG2E, Bb[bidx + 0]));
        float e1 = __builtin_amdgcn_exp2f(fmaf(sc[nt][1], LOG2E, Bb[bidx + 1]));
        float e2 = __builtin_amdgcn_exp2f(fmaf(sc[nt][2], LOG2E, Bb[bidx + 2]));
        float e3 = __builtin_amdgcn_exp2f(fmaf(sc[nt][3], LOG2E, Bb[bidx + 3]));
        lsum[qi] += (e0 + e1) + (e2 + e3);
        unsigned p01 = cvtpk(e0, e1), p23 = cvtpk(e2, e3);
        if (nt == 0) { pb0.u[0] = p01; pb0.u[1] = p23; }
        else if (nt == 1) { pb0.u[2] = p01; pb0.u[3] = p23; }
        else if (nt == 2) { pb1.u[0] = p01; pb1.u[1] = p23; }
        else { pb1.u[2] = p01; pb1.u[3] = p23; }
      }
      // lane's own packed scores ARE the PV B-fragment (V k-axis permuted)
#pragma unroll
      for (int dt = 0; dt < 3; dt++) {
        O[dt][qi] = __builtin_amdgcn_mfma_f32_16x16x32_bf16(vf[dt][0], pb0.v, O[dt][qi], 0, 0, 0);
        O[dt][qi] = __builtin_amdgcn_mfma_f32_16x16x32_bf16(vf[dt][1], pb1.v, O[dt][qi], 0, 0, 0);
      }
    }

    // ---- write next tile into the other buffer (loads drained here) ----
    if (tid < 192 && !last) {
      int nxt = cur ^ 1;
      *(uint4*)&Ks[nxt][krow * 72 + kpos * 8] = k0n;
      *(uint4*)&Ks[nxt][krow * 72 + (kpos + 1) * 8] = k1n;
#pragma unroll
      for (int j = 0; j < 4; j++) {
        unsigned wa = ((const unsigned*)&van)[j], wb = ((const unsigned*)&vbn)[j];
        unsigned pe, po;
        asm("v_perm_b32 %0, %1, %2, %3" : "=v"(pe) : "v"(wb), "v"(wa), "v"(sel_e));
        asm("v_perm_b32 %0, %1, %2, %3" : "=v"(po) : "v"(wb), "v"(wa), "v"(sel_o));
        *(unsigned*)&Vts[nxt][(vdg * 8 + 2 * j + 0) * 72 + vcol] = pe;
        *(unsigned*)&Vts[nxt][(vdg * 8 + 2 * j + 1) * 72 + vcol] = po;
      }
    }
    __syncthreads();
    cur ^= 1;
  }

  // ---- epilogue: reduce denom over quads, normalize, transpose O^T via QP ----
  __syncthreads();  // all waves done reading Bb (aliases QP)
  float inv[2];
#pragma unroll
  for (int qi = 0; qi < 2; qi++) {
    float s = lsum[qi];
    s += __shfl_xor(s, 16, 64);
    s += __shfl_xor(s, 32, 64);
    inv[qi] = __builtin_amdgcn_rcpf(s);
  }
  // wave-local: write O^T (d-adjacent regs packed) into this wave's QP rows [q][d]
#pragma unroll
  for (int dt = 0; dt < 3; dt++)
#pragma unroll
    for (int qi = 0; qi < 2; qi++) {
      unsigned w0 = cvtpk(O[dt][qi][0] * inv[qi], O[dt][qi][1] * inv[qi]);
      unsigned w1 = cvtpk(O[dt][qi][2] * inv[qi], O[dt][qi][3] * inv[qi]);
      uint2 wv = {w0, w1};
      *(uint2*)&QP[(wid * 32 + qi * 16 + lanelo) * 72 + dt * 16 + quad * 4] = wv;
    }
  __asm__ volatile("s_waitcnt lgkmcnt(0)" ::: "memory");  // wave-local transpose
  // read back 16B granules, coalesced global store
#pragma unroll
  for (int s = 0; s < 3; s++) {
    int g = lane + 64 * s;  // 0..191: 32 rows x 6 granules
    int qloc = g / 6, pos = g - qloc * 6;
    uint4 val = *(const uint4*)&QP[(wid * 32 + qloc) * 72 + pos * 8];
    *(uint4*)(ao + (bSL + (size_t)(l0 + wid * 32 + qloc)) * CH + h * DH + pos * 8) = val;
  }
}

// ---------------- launch ----------------
extern "C" void kernel_launch(void* const* d_in, const int* in_sizes, int n_in,
                              void* d_out, int out_size, void* d_ws, size_t ws_size,
                              hipStream_t stream) {
  const float* x = (const float*)d_in[0];
  const float* gamma = (const float*)d_in[1];
  const float* beta = (const float*)d_in[2];
  const float* Wq = (const float*)d_in[3];
  const float* Wk = (const float*)d_in[4];
  const float* Wv = (const float*)d_in[5];
  const float* Wo = (const float*)d_in[6];
  const float* bo = (const float*)d_in[7];
  const float* rel_bias = (const float*)d_in[8];
  const float* fc1_w = (const float*)d_in[9];
  const float* fc1_b = (const float*)d_in[10];
  const float* fc2_w = (const float*)d_in[11];
  const float* fc2_b = (const float*)d_in[12];
  float* out = (float*)d_out;

  const size_t TOKCH = (size_t)NTOK * CH;
  float* ws_f = (float*)d_ws;
  float* yb = ws_f;                            // fp32 y = x + attn-proj (token-major)
  short* wbf    = (short*)(yb + TOKCH);        // bf16 weight pool
  short* tok_bf = wbf + WTOT;                  // (NTOK, 384)
  short* hm     = tok_bf + TOKCH;              // q|k|v head-major, 3*HMS shorts
  short* ao_bf  = hm + 3 * (size_t)HMS;        // (NTOK, 384)
  short* yb_bf  = ao_bf + TOKCH;               // (NTOK, 384)
  short* h1_bf  = yb_bf + TOKCH;               // (NTOK, 1536)

  k_w2bf<<<WTOT / 8 / 256, 256, 0, stream>>>(Wq, Wk, Wv, Wo, fc1_w, fc2_w, wbf);
  k_ln_fused<<<dim3(SL / 32, BATCH), 256, 0, stream>>>(x, gamma, beta, tok_bf);

  // qkv = tok @ [Wq|Wk|Wv]^T  -> head-major q,k,v   (576 blocks, 576%8==0)
  k_gemm_mfma<128, false, false, 0, 8>
      <<<dim3(QKVLD / 128, NTOK / 128), 256, 0, stream>>>(
          tok_bf, wbf + WQKV_OFF, nullptr, nullptr, nullptr, nullptr, nullptr,
          hm, QKVLD, CH);

  k_attn_mfma<<<dim3(SL / 128, NHEAD, BATCH), 256, 0, stream>>>(
      hm, hm + HMS, hm + 2 * (size_t)HMS, rel_bias, ao_bf);

  // y = x + ao @ Wo^T + bo  (residual from x in (B,C,L)) -> yb fp32 + bf16
  // (384 blocks, 384%8==0)
  k_gemm_mfma<64, false, true, 2, 3>
      <<<dim3(CH / 128, NTOK / 64), 256, 0, stream>>>(
          ao_bf, wbf + WO_OFF, bo, x, yb, yb_bf, nullptr, nullptr, CH, CH);

  // h1 = gelu(y @ fc1_w^T + fc1_b) -> bf16   (768 blocks, 768%8==0)
  k_gemm_mfma<128, true, true, 0, 2>
      <<<dim3(CFF / 128, NTOK / 128), 256, 0, stream>>>(
          yb_bf, wbf + F1_OFF, fc1_b, nullptr, nullptr, h1_bf, nullptr, nullptr,
          CFF, CH);

  // out(B,C,L) = y + (h1 @ fc2_w^T + fc2_b)   [direct transposed store]
  // (384 blocks, 384%8==0)
  k_gemm_mfma<64, false, true, 1, 4>
      <<<dim3(CH / 128, NTOK / 64), 256, 0, stream>>>(
          h1_bf, wbf + F2_OFF, fc2_b, yb, nullptr, nullptr, out, nullptr, CH, CFF);
}

// Round 9
// 192.123 us; speedup vs baseline: 1.1323x; 1.0134x over previous
//
#include <hip/hip_runtime.h>
#include <math.h>

#define SL 1024      // sequence length (H*W)
#define CH 384       // channels
#define NHEAD 8
#define DH 48        // head dim (dk == dv)
#define NBIAS 3969
#define NTOK 8192    // B * SL
#define BATCH 8
#define CFF 1536
#define LN_EPS 1e-5f
#define QKVLD 1152
#define HMS 3145728  // shorts per head-major tensor: B*NH*SL*48
#define LOG2E 1.4426950408889634f

// bf16 weight pool layout (element offsets)
#define WQKV_OFF 0
#define WO_OFF   442368
#define F1_OFF   589824
#define F2_OFF   1179648
#define WTOT     1769472

typedef float floatx4 __attribute__((ext_vector_type(4)));
typedef short bf16x8 __attribute__((ext_vector_type(8)));

__device__ __forceinline__ unsigned f2bf_u(float f) {
  unsigned u = __float_as_uint(f);
  return (u + 0x7fffu + ((u >> 16) & 1u)) >> 16;
}
__device__ __forceinline__ unsigned pack2(float a, float b) {
  return f2bf_u(a) | (f2bf_u(b) << 16);
}
// single-instruction packed f32x2 -> bf16x2 (RNE, same as f2bf_u)
__device__ __forceinline__ unsigned cvtpk(float lo, float hi) {
  unsigned r;
  asm("v_cvt_pk_bf16_f32 %0, %1, %2" : "=v"(r) : "v"(lo), "v"(hi));
  return r;
}

// async global->LDS, 16B per lane; lds base must be wave-uniform
__device__ __forceinline__ void gload_lds16(const void* g, void* l) {
  __builtin_amdgcn_global_load_lds(
      (const __attribute__((address_space(1))) void*)g,
      (__attribute__((address_space(3))) void*)l, 16, 0, 0);
}

// ---------------- weights fp32 -> bf16 pool ----------------
__global__ void k_w2bf(const float* __restrict__ Wq, const float* __restrict__ Wk,
                       const float* __restrict__ Wv, const float* __restrict__ Wo,
                       const float* __restrict__ f1, const float* __restrict__ f2,
                       short* __restrict__ dst) {
  size_t i = ((size_t)blockIdx.x * 256 + threadIdx.x) * 8;
  if (i >= WTOT) return;
  const float* s;
  size_t base;
  if (i < 147456)        { s = Wq; base = 0; }
  else if (i < 294912)   { s = Wk; base = 147456; }
  else if (i < WO_OFF)   { s = Wv; base = 294912; }
  else if (i < F1_OFF)   { s = Wo; base = WO_OFF; }
  else if (i < F2_OFF)   { s = f1; base = F1_OFF; }
  else                   { s = f2; base = F2_OFF; }
  const float4* p = (const float4*)(s + (i - base));
  float4 a = p[0], b = p[1];
  uint4 o;
  o.x = pack2(a.x, a.y); o.y = pack2(a.z, a.w);
  o.z = pack2(b.x, b.y); o.w = pack2(b.z, b.w);
  *(uint4*)(dst + i) = o;
}

// ---------------- fused transpose + LayerNorm: x (B,C,L) -> tok_bf (B*L, C) ----
__global__ __launch_bounds__(256) void k_ln_fused(
    const float* __restrict__ x, const float* __restrict__ gamma,
    const float* __restrict__ beta, short* __restrict__ tok) {
  __shared__ float sx[32][385];  // [l][c]
  int b = blockIdx.y, l0 = blockIdx.x * 32;
  int tid = threadIdx.x;
  const float* xb = x + (size_t)b * CH * SL;
  int cr = tid >> 3, ls = (tid & 7) * 4;
#pragma unroll
  for (int c0 = 0; c0 < CH; c0 += 32) {
    int c = c0 + cr;
    float4 v = *(const float4*)(xb + (size_t)c * SL + l0 + ls);
    sx[ls + 0][c] = v.x; sx[ls + 1][c] = v.y;
    sx[ls + 2][c] = v.z; sx[ls + 3][c] = v.w;
  }
  __syncthreads();
  int tl = tid >> 3, p = tid & 7;  // 8 threads per token, 48 channels each
  float vals[48];
  float s = 0.f, q = 0.f;
#pragma unroll
  for (int i = 0; i < 48; i++) {
    float v = sx[tl][p * 48 + i];
    vals[i] = v; s += v; q += v * v;
  }
  s += __shfl_xor(s, 1, 64); q += __shfl_xor(q, 1, 64);
  s += __shfl_xor(s, 2, 64); q += __shfl_xor(q, 2, 64);
  s += __shfl_xor(s, 4, 64); q += __shfl_xor(q, 4, 64);
  float mu = s * (1.0f / CH);
  float rstd = rsqrtf(q * (1.0f / CH) - mu * mu + LN_EPS);
  short* orow = tok + (size_t)(b * SL + l0 + tl) * CH + p * 48;
#pragma unroll
  for (int i = 0; i < 48; i += 2) {
    float a = (vals[i] - mu) * rstd * gamma[p * 48 + i] + beta[p * 48 + i];
    float c = (vals[i + 1] - mu) * rstd * gamma[p * 48 + i + 1] + beta[p * 48 + i + 1];
    *(unsigned*)(orow + i) = pack2(a, c);
  }
}

// ---------------- bf16 MFMA GEMM: C(M,N) = A(M,K) @ W(N,K)^T ----------------
// Tile BMx128, BK=64. 256 thr = 4 waves 2x2; wave-tile (BM/2)x64.
// RES_MODE: 0 none, 1 row-major fp32, 2 x-layout (B,C,L) fp32.
// OUT_MODE bits: 1 f32 row-major Cf, 2 bf16 Cb, 4 f32 (B,C,L) Ct,
//                8 bf16 head-major qkv split (Chm: q|k|v each HMS shorts).
// T1 XCD swizzle: all launches have gridX*gridY divisible by 8; XCD k
// processes a contiguous chunk of the linearized grid (A-panel + B-panel
// working set per chunk < 4MB XCD L2).  [round-8: +6.7us e2e, kept]
// GELU: sigmoid form of tanh approximation (7 VALU + exp2 + rcp vs ~25-30
// op libm erff; max model error <2e-4 at |x|<1.5, h1 scale ~0.4).
template <int BM, bool GELU, bool HAS_BIAS, int RES_MODE, int OUT_MODE>
__global__ __launch_bounds__(256) void k_gemm_mfma(
    const short* __restrict__ A, const short* __restrict__ W,
    const float* __restrict__ bias, const float* __restrict__ res,
    float* __restrict__ Cf, short* __restrict__ Cb, float* __restrict__ Ct,
    short* __restrict__ Chm, int N, int K) {
  constexpr int MI = BM / 32;
  constexpr int ASI = BM * 2 / 64;
  __shared__ short As[BM * 64];
  __shared__ short Bs[128 * 64];
  int tid = threadIdx.x;
  int wid = tid >> 6, lane = tid & 63;
  int lanelo = lane & 15, quad = lane >> 4;
  int wm = wid & 1, wn = wid >> 1;

  // XCD-chunked bijective swizzle (nwg % 8 == 0 for all launches)
  int nbx = (int)gridDim.x;
  int lin = (int)blockIdx.y * nbx + (int)blockIdx.x;
  int chunk = (nbx * (int)gridDim.y) >> 3;
  int wk = (lin & 7) * chunk + (lin >> 3);
  int m0 = (wk / nbx) * BM, n0 = (wk % nbx) * 128;

  const short* Aga[ASI];
  short* Ala[ASI];
#pragma unroll
  for (int s = 0; s < ASI; s++) {
    int p = wid * (BM * 2) + s * 64 + lane;
    int row = p >> 3, ch = (p & 7) ^ (row & 7);
    Aga[s] = A + (size_t)(m0 + row) * K + ch * 8;
    Ala[s] = As + (wid * (BM * 2) + s * 64) * 8;
  }
  const short* Bga[4];
  short* Bla[4];
#pragma unroll
  for (int s = 0; s < 4; s++) {
    int p = wid * 256 + s * 64 + lane;
    int row = p >> 3, ch = (p & 7) ^ (row & 7);
    Bga[s] = W + (size_t)(n0 + row) * K + ch * 8;
    Bla[s] = Bs + (wid * 256 + s * 64) * 8;
  }

  floatx4 acc[MI][4];
#pragma unroll
  for (int i = 0; i < MI; i++)
#pragma unroll
    for (int j = 0; j < 4; j++) acc[i][j] = {0.f, 0.f, 0.f, 0.f};

  int x8 = lanelo & 7;
  int ca0 = (quad ^ x8) * 8;
  int ca1 = ((quad + 4) ^ x8) * 8;

  for (int k0 = 0; k0 < K; k0 += 64) {
    __syncthreads();
#pragma unroll
    for (int s = 0; s < ASI; s++) gload_lds16(Aga[s] + k0, Ala[s]);
#pragma unroll
    for (int s = 0; s < 4; s++) gload_lds16(Bga[s] + k0, Bla[s]);
    __syncthreads();
#pragma unroll
    for (int h = 0; h < 2; h++) {
      int co = h ? ca1 : ca0;
      bf16x8 af[MI], bq[4];
#pragma unroll
      for (int i = 0; i < MI; i++)
        af[i] = *(const bf16x8*)&As[(wm * (BM / 2) + i * 16 + lanelo) * 64 + co];
#pragma unroll
      for (int j = 0; j < 4; j++)
        bq[j] = *(const bf16x8*)&Bs[(wn * 64 + j * 16 + lanelo) * 64 + co];
#pragma unroll
      for (int i = 0; i < MI; i++)
#pragma unroll
        for (int j = 0; j < 4; j++)
          acc[i][j] = __builtin_amdgcn_mfma_f32_16x16x32_bf16(af[i], bq[j], acc[i][j], 0, 0, 0);
    }
  }

  // epilogue: C/D row=(lane>>4)*4+reg, col=lane&15; reg = 4 consecutive tokens.
  int colb = n0 + wn * 64 + lanelo;
  float bvv[4];
#pragma unroll
  for (int j = 0; j < 4; j++) bvv[j] = HAS_BIAS ? bias[colb + j * 16] : 0.0f;
#pragma unroll
  for (int i = 0; i < MI; i++) {
    int r = m0 + wm * (BM / 2) + i * 16 + quad * 4;
    int bb = r >> 10, ll = r & 1023;
#pragma unroll
    for (int j = 0; j < 4; j++) {
      int c = colb + j * 16;
      float4 rv = {0.f, 0.f, 0.f, 0.f};
      if (RES_MODE == 2) rv = *(const float4*)(res + ((size_t)bb * CH + c) * SL + ll);
      float vv[4];
#pragma unroll
      for (int reg = 0; reg < 4; reg++) {
        float v = acc[i][j][reg] + bvv[j];
        if (RES_MODE == 1) v += res[(size_t)(r + reg) * N + c];
        if (RES_MODE == 2) v += (&rv.x)[reg];
        if (GELU) {
          // gelu(v) ~= v * sigmoid(2t), t = sqrt(2/pi)*(v + 0.044715 v^3)
          float t = v * fmaf(v * v, 0.0356774081f, 0.7978845608f);
          float e = __builtin_amdgcn_exp2f(t * -2.8853900817779268f);
          v = v * __builtin_amdgcn_rcpf(e + 1.0f);
        }
        vv[reg] = v;
      }
      if (OUT_MODE & 1) {
#pragma unroll
        for (int reg = 0; reg < 4; reg++) Cf[(size_t)(r + reg) * N + c] = vv[reg];
      }
      if (OUT_MODE & 2) {
#pragma unroll
        for (int reg = 0; reg < 4; reg++) Cb[(size_t)(r + reg) * N + c] = (short)f2bf_u(vv[reg]);
      }
      if (OUT_MODE & 4) {
        float4 ov = {vv[0], vv[1], vv[2], vv[3]};
        *(float4*)(Ct + ((size_t)bb * CH + c) * SL + ll) = ov;
      }
      if (OUT_MODE & 8) {
        int part = c / 384;
        int rem = c - part * 384;
        int hh = rem / 48, dd = rem - hh * 48;
        short* dst = Chm + (size_t)part * HMS +
                     ((size_t)(bb * NHEAD + hh) * SL + ll) * 48 + dd;
#pragma unroll
        for (int reg = 0; reg < 4; reg++) dst[reg * 48] = (short)f2bf_u(vv[reg]);
      }
    }
  }
}

// ---------------- MFMA flash attention, swapped-QK^T, in-register P, ---------
// ---------------- double-buffered K/V staging, VALU-lean softmax ------------
// == round-4 structure + T1 XCD swizzle (round-8 best: 194.7us e2e) ==
// round-9 delta: last-iteration dummy K/V loads guarded out (!last) --
// saves ~12MB redundant HBM fetch per pass.
__global__ __launch_bounds__(256) void k_attn_mfma(
    const short* __restrict__ qh, const short* __restrict__ kh,
    const short* __restrict__ vh, const float* __restrict__ rel_bias,
    short* __restrict__ ao) {
  __shared__ short QP[128 * 72];     // Q (prologue) / bias band (loop) / O^T (epilogue)
  __shared__ short Ks[2][64 * 72];
  __shared__ short Vts[2][48 * 72];  // row=d, col=sigma(k) (PV slot order)
  float* Bb = (float*)QP;            // 1152 floats, aliases QP rows 0..31

  int lin = ((int)blockIdx.z * 8 + (int)blockIdx.y) * 8 + (int)blockIdx.x;
  int wk = (lin & 7) * 64 + (lin >> 3);
  int b = wk >> 6, h = (wk >> 3) & 7;
  int l0 = (wk & 7) * 128;
  int tid = threadIdx.x;
  int wid = tid >> 6, lane = tid & 63;
  int lanelo = lane & 15, quad = lane >> 4;
  size_t hb = ((size_t)b * NHEAD + h) * SL;
  size_t bSL = (size_t)b * SL;
  const short* kbase = kh + hb * 48;
  const short* vbase = vh + hb * 48;

  // ---- stage Q tile (contiguous 12 KB, 768 granules, 3/thread) ----
  {
    const short* qsrc = qh + (hb + l0) * 48;
#pragma unroll
    for (int s = 0; s < 3; s++) {
      int g = tid + 256 * s;
      int row = g / 6, pos = g - row * 6;
      *(uint4*)&QP[row * 72 + pos * 8] = *(const uint4*)(qsrc + g * 8);
    }
  }
  // zero pads (Q 128 rows, both K buffers 64 rows; cols 48..63)
  for (int z = tid; z < 128 * 8; z += 256) {
    int r = z >> 3, u = z & 7;
    ((unsigned*)&QP[r * 72 + 48])[u] = 0u;
    if (r < 64) {
      ((unsigned*)&Ks[0][r * 72 + 48])[u] = 0u;
      ((unsigned*)&Ks[1][r * 72 + 48])[u] = 0u;
    }
  }
  __syncthreads();

  // resident Q B-fragments: [qi][chalf] (lane holds Q[q=lanelo][c=quad*8+j])
  bf16x8 aq[2][2];
#pragma unroll
  for (int qi = 0; qi < 2; qi++) {
    aq[qi][0] = *(const bf16x8*)&QP[(wid * 32 + qi * 16 + lanelo) * 72 + quad * 8];
    aq[qi][1] = *(const bf16x8*)&QP[(wid * 32 + qi * 16 + lanelo) * 72 + 32 + quad * 8];
  }
  __syncthreads();  // aq consumed; QP region may be overwritten by bias band

  // staging assignment (tid<192): K granule pair kg=2*tid; V token-pair+d-group
  int kg = 2 * tid;
  int krow = kg / 6, kpos = kg - krow * 6;  // kg even -> kpos in {0,2,4}
  int vmp = tid & 31, vdg = tid >> 5;
  // V column permutation sigma(k): k = g*32+s*16+Q*4+r -> col = g*32+Q*8+s*4+r
  int kk = 2 * vmp;
  int vcol = (kk & 3) + ((kk >> 2) & 3) * 8 + ((kk >> 4) & 1) * 4 + (kk >> 5) * 32;
  unsigned sel_e = 0x05040100u, sel_o = 0x07060302u;  // v_perm selectors

  // ---- stage bias band (pre-scaled by log2e) into QP alias ----
  {
    const float* bsrc = rel_bias + h * NBIAS + (929 - l0);
    for (int j = tid; j < 1152; j += 256) Bb[j] = bsrc[j] * LOG2E;
  }
  // ---- stage K/V tile 0 into buffer 0 ----
  if (tid < 192) {
    const short* ksrc = kbase + kg * 8;
    uint4 k0 = *(const uint4*)(ksrc);
    uint4 k1 = *(const uint4*)(ksrc + 8);
    const short* vs = vbase + (size_t)kk * 48 + vdg * 8;
    uint4 va = *(const uint4*)vs;
    uint4 vb = *(const uint4*)(vs + 48);
    *(uint4*)&Ks[0][krow * 72 + kpos * 8] = k0;
    *(uint4*)&Ks[0][krow * 72 + (kpos + 1) * 8] = k1;
#pragma unroll
    for (int j = 0; j < 4; j++) {
      unsigned wa = ((const unsigned*)&va)[j], wb = ((const unsigned*)&vb)[j];
      unsigned pe, po;
      asm("v_perm_b32 %0, %1, %2, %3" : "=v"(pe) : "v"(wb), "v"(wa), "v"(sel_e));
      asm("v_perm_b32 %0, %1, %2, %3" : "=v"(po) : "v"(wb), "v"(wa), "v"(sel_o));
      *(unsigned*)&Vts[0][(vdg * 8 + 2 * j + 0) * 72 + vcol] = pe;
      *(unsigned*)&Vts[0][(vdg * 8 + 2 * j + 1) * 72 + vcol] = po;
    }
  }
  __syncthreads();

  floatx4 O[3][2];  // O^T accum: [dt][qi], C-layout row=d=quad*4+reg, col=q=lanelo
#pragma unroll
  for (int dt = 0; dt < 3; dt++)
#pragma unroll
    for (int qi = 0; qi < 2; qi++) O[dt][qi] = {0.f, 0.f, 0.f, 0.f};
  float lsum[2] = {0.f, 0.f};
  // bias LDS offset: j = k - (l - l0) + 127; k = mt + nt*16 + quad*4 + reg
  int boff[2];
#pragma unroll
  for (int qi = 0; qi < 2; qi++)
    boff[qi] = 127 + quad * 4 - (wid * 32 + qi * 16 + lanelo);

  int cur = 0;
  for (int mt = 0; mt < SL; mt += 64) {
    bool last = (mt + 64 >= SL);
    uint4 k0n, k1n, van, vbn;
    if (tid < 192 && !last) {  // issue next-tile global loads EARLY
      int mtn = mt + 64;
      const short* ksrc = kbase + (size_t)mtn * 48 + kg * 8;
      k0n = *(const uint4*)(ksrc);
      k1n = *(const uint4*)(ksrc + 8);
      const short* vs = vbase + (size_t)(mtn + kk) * 48 + vdg * 8;
      van = *(const uint4*)vs;
      vbn = *(const uint4*)(vs + 48);
    }

    // ---- compute tile from buffer cur ----
    // K A-fragments (lane holds K[k=nt*16+lanelo][c=quad*8+j])
    bf16x8 kb[4][2];
#pragma unroll
    for (int nt = 0; nt < 4; nt++) {
      kb[nt][0] = *(const bf16x8*)&Ks[cur][(nt * 16 + lanelo) * 72 + quad * 8];
      kb[nt][1] = *(const bf16x8*)&Ks[cur][(nt * 16 + lanelo) * 72 + 32 + quad * 8];
    }
    // V^T A-fragments (lane holds V^T[d=dt*16+lanelo][slot g*32+quad*8+j])
    bf16x8 vf[3][2];
#pragma unroll
    for (int dt = 0; dt < 3; dt++) {
      vf[dt][0] = *(const bf16x8*)&Vts[cur][(dt * 16 + lanelo) * 72 + quad * 8];
      vf[dt][1] = *(const bf16x8*)&Vts[cur][(dt * 16 + lanelo) * 72 + 32 + quad * 8];
    }

#pragma unroll
    for (int qi = 0; qi < 2; qi++) {
      // S^T = K @ Q^T: C row=k=quad*4+reg(+nt*16), col=q=lanelo
      floatx4 sc[4];
#pragma unroll
      for (int nt = 0; nt < 4; nt++) {
        floatx4 a = {0.f, 0.f, 0.f, 0.f};
        a = __builtin_amdgcn_mfma_f32_16x16x32_bf16(kb[nt][0], aq[qi][0], a, 0, 0, 0);
        a = __builtin_amdgcn_mfma_f32_16x16x32_bf16(kb[nt][1], aq[qi][1], a, 0, 0, 0);
        sc[nt] = a;
      }
      // softmax (no running max: scores bounded), pack in-register via cvt_pk
      union U8 { unsigned u[4]; bf16x8 v; };
      U8 pb0, pb1;
#pragma unroll
      for (int nt = 0; nt < 4; nt++) {
        int bidx = boff[qi] + mt + nt * 16;
        float e0 = __builtin_amdgcn_exp2f(fmaf(sc[nt][0], LOG2E, Bb[bidx + 0]));
        float e1 = __builtin_amdgcn_exp2f(fmaf(sc[nt][1], LOG2E, Bb[bidx + 1]));
        float e2 = __builtin_amdgcn_exp2f(fmaf(sc[nt][2], LOG2E, Bb[bidx + 2]));
        float e3 = __builtin_amdgcn_exp2f(fmaf(sc[nt][3], LOG2E, Bb[bidx + 3]));
        lsum[qi] += (e0 + e1) + (e2 + e3);
        unsigned p01 = cvtpk(e0, e1), p23 = cvtpk(e2, e3);
        if (nt == 0) { pb0.u[0] = p01; pb0.u[1] = p23; }
        else if (nt == 1) { pb0.u[2] = p01; pb0.u[3] = p23; }
        else if (nt == 2) { pb1.u[0] = p01; pb1.u[1] = p23; }
        else { pb1.u[2] = p01; pb1.u[3] = p23; }
      }
      // lane's own packed scores ARE the PV B-fragment (V k-axis permuted)
#pragma unroll
      for (int dt = 0; dt < 3; dt++) {
        O[dt][qi] = __builtin_amdgcn_mfma_f32_16x16x32_bf16(vf[dt][0], pb0.v, O[dt][qi], 0, 0, 0);
        O[dt][qi] = __builtin_amdgcn_mfma_f32_16x16x32_bf16(vf[dt][1], pb1.v, O[dt][qi], 0, 0, 0);
      }
    }

    // ---- write next tile into the other buffer (loads drained here) ----
    if (tid < 192 && !last) {
      int nxt = cur ^ 1;
      *(uint4*)&Ks[nxt][krow * 72 + kpos * 8] = k0n;
      *(uint4*)&Ks[nxt][krow * 72 + (kpos + 1) * 8] = k1n;
#pragma unroll
      for (int j = 0; j < 4; j++) {
        unsigned wa = ((const unsigned*)&van)[j], wb = ((const unsigned*)&vbn)[j];
        unsigned pe, po;
        asm("v_perm_b32 %0, %1, %2, %3" : "=v"(pe) : "v"(wb), "v"(wa), "v"(sel_e));
        asm("v_perm_b32 %0, %1, %2, %3" : "=v"(po) : "v"(wb), "v"(wa), "v"(sel_o));
        *(unsigned*)&Vts[nxt][(vdg * 8 + 2 * j + 0) * 72 + vcol] = pe;
        *(unsigned*)&Vts[nxt][(vdg * 8 + 2 * j + 1) * 72 + vcol] = po;
      }
    }
    __syncthreads();
    cur ^= 1;
  }

  // ---- epilogue: reduce denom over quads, normalize, transpose O^T via QP ----
  __syncthreads();  // all waves done reading Bb (aliases QP)
  float inv[2];
#pragma unroll
  for (int qi = 0; qi < 2; qi++) {
    float s = lsum[qi];
    s += __shfl_xor(s, 16, 64);
    s += __shfl_xor(s, 32, 64);
    inv[qi] = __builtin_amdgcn_rcpf(s);
  }
  // wave-local: write O^T (d-adjacent regs packed) into this wave's QP rows [q][d]
#pragma unroll
  for (int dt = 0; dt < 3; dt++)
#pragma unroll
    for (int qi = 0; qi < 2; qi++) {
      unsigned w0 = cvtpk(O[dt][qi][0] * inv[qi], O[dt][qi][1] * inv[qi]);
      unsigned w1 = cvtpk(O[dt][qi][2] * inv[qi], O[dt][qi][3] * inv[qi]);
      uint2 wv = {w0, w1};
      *(uint2*)&QP[(wid * 32 + qi * 16 + lanelo) * 72 + dt * 16 + quad * 4] = wv;
    }
  __asm__ volatile("s_waitcnt lgkmcnt(0)" ::: "memory");  // wave-local transpose
  // read back 16B granules, coalesced global store
#pragma unroll
  for (int s = 0; s < 3; s++) {
    int g = lane + 64 * s;  // 0..191: 32 rows x 6 granules
    int qloc = g / 6, pos = g - qloc * 6;
    uint4 val = *(const uint4*)&QP[(wid * 32 + qloc) * 72 + pos * 8];
    *(uint4*)(ao + (bSL + (size_t)(l0 + wid * 32 + qloc)) * CH + h * DH + pos * 8) = val;
  }
}

// ---------------- launch ----------------
extern "C" void kernel_launch(void* const* d_in, const int* in_sizes, int n_in,
                              void* d_out, int out_size, void* d_ws, size_t ws_size,
                              hipStream_t stream) {
  const float* x = (const float*)d_in[0];
  const float* gamma = (const float*)d_in[1];
  const float* beta = (const float*)d_in[2];
  const float* Wq = (const float*)d_in[3];
  const float* Wk = (const float*)d_in[4];
  const float* Wv = (const float*)d_in[5];
  const float* Wo = (const float*)d_in[6];
  const float* bo = (const float*)d_in[7];
  const float* rel_bias = (const float*)d_in[8];
  const float* fc1_w = (const float*)d_in[9];
  const float* fc1_b = (const float*)d_in[10];
  const float* fc2_w = (const float*)d_in[11];
  const float* fc2_b = (const float*)d_in[12];
  float* out = (float*)d_out;

  const size_t TOKCH = (size_t)NTOK * CH;
  float* ws_f = (float*)d_ws;
  float* yb = ws_f;                            // fp32 y = x + attn-proj (token-major)
  short* wbf    = (short*)(yb + TOKCH);        // bf16 weight pool
  short* tok_bf = wbf + WTOT;                  // (NTOK, 384)
  short* hm     = tok_bf + TOKCH;              // q|k|v head-major, 3*HMS shorts
  short* ao_bf  = hm + 3 * (size_t)HMS;        // (NTOK, 384)
  short* yb_bf  = ao_bf + TOKCH;               // (NTOK, 384)
  short* h1_bf  = yb_bf + TOKCH;               // (NTOK, 1536)

  k_w2bf<<<WTOT / 8 / 256, 256, 0, stream>>>(Wq, Wk, Wv, Wo, fc1_w, fc2_w, wbf);
  k_ln_fused<<<dim3(SL / 32, BATCH), 256, 0, stream>>>(x, gamma, beta, tok_bf);

  // qkv = tok @ [Wq|Wk|Wv]^T  -> head-major q,k,v   (576 blocks, 576%8==0)
  k_gemm_mfma<128, false, false, 0, 8>
      <<<dim3(QKVLD / 128, NTOK / 128), 256, 0, stream>>>(
          tok_bf, wbf + WQKV_OFF, nullptr, nullptr, nullptr, nullptr, nullptr,
          hm, QKVLD, CH);

  k_attn_mfma<<<dim3(SL / 128, NHEAD, BATCH), 256, 0, stream>>>(
      hm, hm + HMS, hm + 2 * (size_t)HMS, rel_bias, ao_bf);

  // y = x + ao @ Wo^T + bo  (residual from x in (B,C,L)) -> yb fp32 + bf16
  // (384 blocks, 384%8==0)
  k_gemm_mfma<64, false, true, 2, 3>
      <<<dim3(CH / 128, NTOK / 64), 256, 0, stream>>>(
          ao_bf, wbf + WO_OFF, bo, x, yb, yb_bf, nullptr, nullptr, CH, CH);

  // h1 = gelu(y @ fc1_w^T + fc1_b) -> bf16   (768 blocks, 768%8==0)
  k_gemm_mfma<128, true, true, 0, 2>
      <<<dim3(CFF / 128, NTOK / 128), 256, 0, stream>>>(
          yb_bf, wbf + F1_OFF, fc1_b, nullptr, nullptr, h1_bf, nullptr, nullptr,
          CFF, CH);

  // out(B,C,L) = y + (h1 @ fc2_w^T + fc2_b)   [direct transposed store]
  // (384 blocks, 384%8==0)
  k_gemm_mfma<64, false, true, 1, 4>
      <<<dim3(CH / 128, NTOK / 64), 256, 0, stream>>>(
          h1_bf, wbf + F2_OFF, fc2_b, yb, nullptr, nullptr, out, nullptr, CH, CFF);
}